// Round 1
// 616.823 us; speedup vs baseline: 1.0548x; 1.0548x over previous
//
#include <hip/hip_runtime.h>
#include <math.h>

// ---------------- constants ----------------
constexpr int Bv = 2, Nv = 2048, NCv = 256;
constexpr int CSv = 384, CCONDv = 256;
constexpr int CHv = 16, Hv = 12, PQKv = 4, PVv = 8;
constexpr int BQv = 32, BKv = 128, NBLKv = 64;
constexpr int HC = Hv * CHv;               // 192
constexpr int QPD = Hv * PQKv * 3;         // 144
constexpr int FEAT = 960;                  // H*CONCAT
constexpr int PROJW = 1152;                // q(192)+k(192)+v(192)+qp(144)+kvp(432)
constexpr float S1 = 0.14433756729740643f; // sqrt(1/48)
constexpr float S2 = 0.5773502691896258f;  // sqrt(1/3)
constexpr float HWS = 0.13608276348795434f;// sqrt(1/54)

typedef __attribute__((ext_vector_type(8))) short bf16x8;
typedef __attribute__((ext_vector_type(4))) float f32x4;

__device__ __forceinline__ short f2bf(float f) {
    unsigned u = __float_as_uint(f);
    u += 0x7FFF + ((u >> 16) & 1);
    return (short)(u >> 16);
}
__device__ __forceinline__ float bf2f(short s) {
    return __uint_as_float(((unsigned)(unsigned short)s) << 16);
}
__device__ __forceinline__ unsigned pk2(short lo, short hi) {
    return ((unsigned)(unsigned short)lo) | (((unsigned)(unsigned short)hi) << 16);
}

// ---------------- helpers ----------------
__device__ __forceinline__ float blockReduceSum(float v, volatile float* red, int t, int nthr) {
    #pragma unroll
    for (int off = 32; off > 0; off >>= 1) v += __shfl_down(v, off, 64);
    int wid = t >> 6, lane = t & 63, nw = nthr >> 6;
    __syncthreads();
    if (lane == 0) red[wid] = v;
    __syncthreads();
    float r = 0.f;
    for (int w = 0; w < nw; ++w) r += red[w];
    return r;
}

// ---------------- W0: convert weights to bf16 ----------------
__global__ __launch_bounds__(256) void k_wcvt(const float* __restrict__ Wq,
                                              const float* __restrict__ Wk,
                                              const float* __restrict__ Wv,
                                              const float* __restrict__ Wqp,
                                              const float* __restrict__ Wkvp,
                                              const float* __restrict__ Wg,
                                              const float* __restrict__ Wnb,
                                              short* __restrict__ wsW,
                                              short* __restrict__ wsW2) {
    int i4 = blockIdx.x * 256 + threadIdx.x;     // one float4 per thread
    int off = i4 * 4;
    const float* src;
    short* dst;
    int rel;
    if (off < 442368) {
        dst = wsW; rel = off;
        if (rel < 73728) src = Wq;
        else if (rel < 147456) { src = Wk; rel -= 73728; }
        else if (rel < 221184) { src = Wv; rel -= 147456; }
        else if (rel < 276480) { src = Wqp; rel -= 221184; }
        else { src = Wkvp; rel -= 276480; }
        float4 v = *(const float4*)(src + rel);
        *(uint2*)(dst + off) = make_uint2(pk2(f2bf(v.x), f2bf(v.y)), pk2(f2bf(v.z), f2bf(v.w)));
    } else if (off < 442368 + 196608) {
        int o2 = off - 442368;
        rel = o2;
        if (rel < 98304) src = Wg; else { src = Wnb; rel -= 98304; }
        float4 v = *(const float4*)(src + rel);
        *(uint2*)(wsW2 + o2) = make_uint2(pk2(f2bf(v.x), f2bf(v.y)), pk2(f2bf(v.z), f2bf(v.w)));
    }
}

// ---------------- generic bf16 GEMM: C[m][n] = sum_k A[m][k]*B[n][k] ----------------
__global__ __launch_bounds__(256) void k_gemm_bt(const short* __restrict__ A,
                                                 const short* __restrict__ B,
                                                 float* __restrict__ C,
                                                 int K, int ldc) {
    __shared__ short As[128 * 40];
    __shared__ short Bs[128 * 40];
    int t = threadIdx.x;
    int m0 = blockIdx.x * 128, n0 = blockIdx.y * 128;
    int wv = t >> 6, lane = t & 63, lr = lane & 15, quad = lane >> 4;
    int mq = (wv & 1) * 64, nq = (wv >> 1) * 64;
    f32x4 acc[4][4];
    #pragma unroll
    for (int i = 0; i < 4; ++i)
        #pragma unroll
        for (int j = 0; j < 4; ++j) acc[i][j] = 0;

    int r0 = t >> 2, c8 = (t & 3) * 8;
    int r1 = (t + 256) >> 2, c81 = ((t + 256) & 3) * 8;

    for (int k0 = 0; k0 < K; k0 += 32) {
        uint4 a0 = *(const uint4*)(A + (size_t)(m0 + r0) * K + k0 + c8);
        uint4 a1 = *(const uint4*)(A + (size_t)(m0 + r1) * K + k0 + c81);
        uint4 b0 = *(const uint4*)(B + (size_t)(n0 + r0) * K + k0 + c8);
        uint4 b1 = *(const uint4*)(B + (size_t)(n0 + r1) * K + k0 + c81);
        *(uint4*)&As[r0 * 40 + c8] = a0;
        *(uint4*)&As[r1 * 40 + c81] = a1;
        *(uint4*)&Bs[r0 * 40 + c8] = b0;
        *(uint4*)&Bs[r1 * 40 + c81] = b1;
        __syncthreads();
        bf16x8 af[4], bf[4];
        #pragma unroll
        for (int i = 0; i < 4; ++i) {
            af[i] = *(const bf16x8*)&As[(mq + i * 16 + lr) * 40 + quad * 8];
            bf[i] = *(const bf16x8*)&Bs[(nq + i * 16 + lr) * 40 + quad * 8];
        }
        #pragma unroll
        for (int i = 0; i < 4; ++i)
            #pragma unroll
            for (int j = 0; j < 4; ++j)
                acc[i][j] = __builtin_amdgcn_mfma_f32_16x16x32_bf16(af[i], bf[j], acc[i][j], 0, 0, 0);
        __syncthreads();
    }
    #pragma unroll
    for (int i = 0; i < 4; ++i) {
        #pragma unroll
        for (int j = 0; j < 4; ++j) {
            int col = n0 + nq + j * 16 + lr;
            #pragma unroll
            for (int r = 0; r < 4; ++r) {
                int row = m0 + mq + i * 16 + quad * 4 + r;
                C[(size_t)row * ldc + col] = acc[i][j][r];
            }
        }
    }
}

// ---------------- K1: LN(cond) -> bf16 ----------------
__global__ __launch_bounds__(256) void k_condln(const float* __restrict__ cond,
                                                const float* __restrict__ lnw,
                                                short* __restrict__ cnbf) {
    __shared__ float red[4];
    int row = blockIdx.x;
    int t = threadIdx.x;
    float c = cond[row * CCONDv + t];
    float mu = blockReduceSum(c, red, t, 256) * (1.f / CCONDv);
    float d = c - mu;
    float var = blockReduceSum(d * d, red, t, 256) * (1.f / CCONDv);
    cnbf[row * CCONDv + t] = f2bf(d * rsqrtf(var + 1e-5f) * lnw[t]);
}

// ---------------- K2: LN(s) + gather gate/bias -> s2 (bf16) ----------------
__global__ __launch_bounds__(128) void k_s2(const float* __restrict__ s,
                                            const float* __restrict__ gb,
                                            const float* __restrict__ bg,
                                            const int* __restrict__ cidx,
                                            const float* __restrict__ smask,
                                            short* __restrict__ s2bf) {
    __shared__ float red[4];
    int row = blockIdx.x;
    int t = threadIdx.x;
    const float* sr = s + (size_t)row * CSv;
    float x0 = sr[t], x1 = sr[t + 128], x2 = sr[t + 256];
    float mu = blockReduceSum(x0 + x1 + x2, red, t, 128) * (1.f / CSv);
    float d0 = x0 - mu, d1 = x1 - mu, d2 = x2 - mu;
    float var = blockReduceSum(d0 * d0 + d1 * d1 + d2 * d2, red, t, 128) * (1.f / CSv);
    float rs = rsqrtf(var + 1e-5f);
    int b = row / Nv;
    int ci = cidx[row];
    float m = smask[row];
    const float* gbr = gb + (size_t)(b * NCv + ci) * 768;
    float dd[3] = {d0, d1, d2};
    #pragma unroll
    for (int j = 0; j < 3; ++j) {
        int cc = t + j * 128;
        float sn = dd[j] * rs;
        float g = (gbr[cc] + bg[cc]) * m, bi = gbr[384 + cc] * m;
        s2bf[(size_t)row * CSv + cc] = f2bf(sn * (1.f / (1.f + expf(-g))) + bi);
    }
}

// ---------------- K3b: point rotation + qsq/ksq from proj ----------------
__global__ __launch_bounds__(192) void k_post(const float* __restrict__ proj,
                                              const float* __restrict__ rots,
                                              const float* __restrict__ trans,
                                              float* __restrict__ qpts,
                                              float* __restrict__ kpts,
                                              float* __restrict__ vpts,
                                              float* __restrict__ qsq,
                                              float* __restrict__ ksq) {
    __shared__ float R[9], tr[3];
    int row = blockIdx.x;
    int t = threadIdx.x;
    if (t < 9) R[t] = rots[(size_t)row * 9 + t];
    if (t < 3) tr[t] = trans[(size_t)row * 3 + t];
    __syncthreads();
    const float* pr = proj + (size_t)row * PROJW + 576;
    float x = pr[t * 3 + 0], y = pr[t * 3 + 1], z = pr[t * 3 + 2];
    float ox = R[0] * x + R[1] * y + R[2] * z + tr[0];
    float oy = R[3] * x + R[4] * y + R[5] * z + tr[1];
    float oz = R[6] * x + R[7] * y + R[8] * z + tr[2];
    float sq = ox * ox + oy * oy + oz * oz;
    if (t < 48) {
        qpts[(size_t)row * QPD + t * 3 + 0] = ox;
        qpts[(size_t)row * QPD + t * 3 + 1] = oy;
        qpts[(size_t)row * QPD + t * 3 + 2] = oz;
        float s4 = sq + __shfl_xor(sq, 1, 64);
        s4 += __shfl_xor(s4, 2, 64);
        if ((t & 3) == 0) qsq[(size_t)row * Hv + (t >> 2)] = s4;
    } else {
        int p = t - 48;
        int h = p / 12, pp = p % 12;
        if (pp < PQKv) {
            kpts[(size_t)row * QPD + (h * PQKv + pp) * 3 + 0] = ox;
            kpts[(size_t)row * QPD + (h * PQKv + pp) * 3 + 1] = oy;
            kpts[(size_t)row * QPD + (h * PQKv + pp) * 3 + 2] = oz;
            float s4 = sq + __shfl_xor(sq, 1, 64);
            s4 += __shfl_xor(s4, 2, 64);
            if (pp == 0) ksq[(size_t)row * Hv + h] = s4;
        } else {
            int vi = h * PVv + pp - PQKv;
            vpts[(size_t)row * (Hv * PVv * 3) + vi * 3 + 0] = ox;
            vpts[(size_t)row * (Hv * PVv * 3) + vi * 3 + 1] = oy;
            vpts[(size_t)row * (Hv * PVv * 3) + vi * 3 + 2] = oz;
        }
    }
}

// ---------------- K4a: precompute folded z-proj weights ----------------
__global__ __launch_bounds__(256) void k_prep(const float* __restrict__ Wb,
                                              const float* __restrict__ Wdz,
                                              const float* __restrict__ lnw,
                                              const float* __restrict__ lnb,
                                              short* __restrict__ wp,
                                              float* __restrict__ SB) {
    int t = threadIdx.x;
    if (t < 176) {
        int c = t >> 2, q = t & 3;
        const float* wrow = (c < 12) ? (Wb + (size_t)c * 128) : (Wdz + (size_t)(c - 12) * 128);
        float sacc = 0.f, bacc = 0.f;
        for (int i = q * 32; i < q * 32 + 32; ++i) {
            float wf = wrow[i] * lnw[i];
            short bs = f2bf(wf);
            wp[c * 128 + i] = bs;
            sacc += bf2f(bs);
            bacc += lnb[i] * wrow[i];
        }
        sacc += __shfl_xor(sacc, 1, 64); sacc += __shfl_xor(sacc, 2, 64);
        bacc += __shfl_xor(bacc, 1, 64); bacc += __shfl_xor(bacc, 2, 64);
        if (q == 0) { SB[c] = sacc; SB[48 + c] = bacc; }
    }
    for (int i = t; i < 512; i += 256) wp[44 * 128 + i] = 0;
    if (t >= 176 && t < 180) { SB[t - 132] = 0.f; SB[48 + t - 132] = 0.f; }
}

// ---------------- K4b: fused LN(z)+proj via bf16 MFMA ----------------
// bbias2 now bf16 with S2 pre-folded (halves the 25 MB round-trip).
__global__ __launch_bounds__(256) void k_zproj2(const float* __restrict__ z,
                                                const short* __restrict__ wp,
                                                const float* __restrict__ SB,
                                                short* __restrict__ bbias2,
                                                short* __restrict__ pairzT) {
    __shared__ short zbuf[128 * 136];
    __shared__ short wbuf[48 * 136];
    __shared__ float muL[128], rsL[128], SL[48], BL[48];
    int t = threadIdx.x;
    int bid = blockIdx.x;
    int bblk = bid >> 5, qq = bid & 31;
    size_t row0 = (size_t)bid * 128;

    for (int idx = t; idx < 768; idx += 256) {
        int c = idx >> 4, k8 = idx & 15;
        uint4 v = *(const uint4*)(wp + c * 128 + k8 * 8);
        *(uint4*)&wbuf[c * 136 + k8 * 8] = v;
    }
    if (t < 96) {
        float v = SB[t];
        if (t < 48) SL[t] = v; else BL[t - 48] = v;
    }

    const float4* zsrc = (const float4*)(z + row0 * 128);
    #pragma unroll
    for (int it = 0; it < 16; ++it) {
        int f = it * 256 + t;
        int r = f >> 5, c4 = f & 31;
        float4 v = zsrc[f];
        short s0 = f2bf(v.x), s1 = f2bf(v.y), s2v = f2bf(v.z), s3 = f2bf(v.w);
        *(uint2*)&zbuf[r * 136 + c4 * 4] = make_uint2(pk2(s0, s1), pk2(s2v, s3));
        float sm = v.x + v.y + v.z + v.w;
        float sq = v.x * v.x + v.y * v.y + v.z * v.z + v.w * v.w;
        #pragma unroll
        for (int off = 1; off <= 16; off <<= 1) {
            sm += __shfl_xor(sm, off, 64);
            sq += __shfl_xor(sq, off, 64);
        }
        if ((t & 31) == 0) {
            float mu = sm * (1.f / 128.f);
            float var = sq * (1.f / 128.f) - mu * mu;
            muL[r] = mu;
            rsL[r] = rsqrtf(var + 1e-5f);
        }
    }
    __syncthreads();

    int wv = t >> 6, lane = t & 63;
    int lr = lane & 15, quad = lane >> 4;
    int mb = wv * 32;
    f32x4 acc[2][3];
    #pragma unroll
    for (int i = 0; i < 2; ++i)
        #pragma unroll
        for (int j = 0; j < 3; ++j) acc[i][j] = 0;
    #pragma unroll
    for (int kt = 0; kt < 4; ++kt) {
        int ko = kt * 32 + quad * 8;
        bf16x8 a0 = *(const bf16x8*)&zbuf[(mb + lr) * 136 + ko];
        bf16x8 a1 = *(const bf16x8*)&zbuf[(mb + 16 + lr) * 136 + ko];
        bf16x8 b0 = *(const bf16x8*)&wbuf[lr * 136 + ko];
        bf16x8 b1 = *(const bf16x8*)&wbuf[(16 + lr) * 136 + ko];
        bf16x8 b2 = *(const bf16x8*)&wbuf[(32 + lr) * 136 + ko];
        acc[0][0] = __builtin_amdgcn_mfma_f32_16x16x32_bf16(a0, b0, acc[0][0], 0, 0, 0);
        acc[0][1] = __builtin_amdgcn_mfma_f32_16x16x32_bf16(a0, b1, acc[0][1], 0, 0, 0);
        acc[0][2] = __builtin_amdgcn_mfma_f32_16x16x32_bf16(a0, b2, acc[0][2], 0, 0, 0);
        acc[1][0] = __builtin_amdgcn_mfma_f32_16x16x32_bf16(a1, b0, acc[1][0], 0, 0, 0);
        acc[1][1] = __builtin_amdgcn_mfma_f32_16x16x32_bf16(a1, b1, acc[1][1], 0, 0, 0);
        acc[1][2] = __builtin_amdgcn_mfma_f32_16x16x32_bf16(a1, b2, acc[1][2], 0, 0, 0);
    }

    short* bb_base = bbias2 + (size_t)(bblk * 12) * 4096 + qq * 128;
    short* pz_base = pairzT + (size_t)bid * 32 * 128;
    #pragma unroll
    for (int mt = 0; mt < 2; ++mt) {
        #pragma unroll
        for (int nt = 0; nt < 3; ++nt) {
            int col = nt * 16 + lr;
            int kbase = mb + mt * 16 + quad * 4;
            float ov[4];
            #pragma unroll
            for (int r4 = 0; r4 < 4; ++r4) {
                int rl = kbase + r4;
                ov[r4] = rsL[rl] * (acc[mt][nt][r4] - muL[rl] * SL[col]) + BL[col];
            }
            if (col < 12) {
                *(uint2*)&bb_base[(size_t)col * 4096 + kbase] =
                    make_uint2(pk2(f2bf(S2 * ov[0]), f2bf(S2 * ov[1])),
                               pk2(f2bf(S2 * ov[2]), f2bf(S2 * ov[3])));
            } else if (col < 44) {
                int c = col - 12;
                *(uint2*)&pz_base[c * 128 + kbase] =
                    make_uint2(pk2(f2bf(ov[0]), f2bf(ov[1])), pk2(f2bf(ov[2]), f2bf(ov[3])));
            }
        }
    }
}

// ---------------- K5a: attention logits+softmax+AV via MFMA ----------------
// grid = B*NBLK*6 (head-pairs); 512 threads = 8 waves; 3 blocks/CU (52 KB LDS).
__global__ __launch_bounds__(512, 6) void k_attn_main(const float* __restrict__ proj,
                                                      const float* __restrict__ qpts,
                                                      const float* __restrict__ kpts,
                                                      const float* __restrict__ vpts,
                                                      const float* __restrict__ qsq,
                                                      const float* __restrict__ ksq,
                                                      const short* __restrict__ bbias2,
                                                      const float* __restrict__ smask,
                                                      const float* __restrict__ head_w,
                                                      short* __restrict__ Aws,
                                                      float* __restrict__ optraw,
                                                      float* __restrict__ feats) {
    __shared__ short kfrag[128 * 40];
    __shared__ short qfrag[32 * 40];
    __shared__ short vtileT[48 * 136];     // transposed V: [c][k], b128-readable
    __shared__ float sc[32 * 132];
    __shared__ short Abuf[32 * 136];
    __shared__ float rowb[32], qmL[32], colb[128], kmL[128];
    __shared__ int   nkgL[128];

    int t = threadIdx.x;
    int hp = blockIdx.x % 6;               // head-pair index
    int bblk = blockIdx.x / 6;
    int b = bblk >> 6, blk = bblk & 63;
    int wv = t >> 6, lane = t & 63;
    int lr = lane & 15, quad = lane >> 4;

    if (t < 128) {
        int nkrel = blk * BQv + t - 48;
        bool valid = (nkrel >= 0) && (nkrel < Nv);
        int nkg = valid ? (b * Nv + nkrel) : -1;
        nkgL[t] = nkg;
        kmL[t] = valid ? smask[nkg] : 0.f;
    }
    {   // zero pad rows 40..47 of vtileT once (never overwritten)
        int c = 40 + (t >> 6), k2 = (t & 63) * 2;
        *(unsigned*)&vtileT[c * 136 + k2] = 0;
    }
    __syncthreads();

    for (int hh = 0; hh < 2; ++hh) {
        int h = hp * 2 + hh;
        float hw = log1pf(expf(head_w[h])) * HWS;

        // ---- stage K-frag, Q-frag, V-tile(transposed), biases ----
        {
            int k = t >> 2, c4 = (t & 3) << 2;
            int g = nkgL[k];
            float4 v = (g >= 0) ? *(const float4*)&proj[(size_t)g * PROJW + 192 + h * 16 + c4]
                                : make_float4(0, 0, 0, 0);
            *(uint2*)&kfrag[k * 40 + c4] =
                make_uint2(pk2(f2bf(v.x), f2bf(v.y)), pk2(f2bf(v.z), f2bf(v.w)));
            kfrag[k * 40 + 28 + (t & 3)] = 0;
        }
        if (t < 384) {
            int k = t / 3, c4 = (t % 3) * 4;
            int g = nkgL[k];
            float4 v = (g >= 0) ? *(const float4*)&kpts[(size_t)g * QPD + h * 12 + c4]
                                : make_float4(0, 0, 0, 0);
            *(uint2*)&kfrag[k * 40 + 16 + c4] =
                make_uint2(pk2(f2bf(v.x), f2bf(v.y)), pk2(f2bf(v.z), f2bf(v.w)));
        }
        if (t < 128) {
            int g = nkgL[t];
            colb[t] = (g >= 0) ? (-0.5f * hw * ksq[(size_t)g * Hv + h]) : 0.f;
            int q = t >> 2, c4 = (t & 3) << 2;
            int nqg = b * Nv + blk * BQv + q;
            float4 v = *(const float4*)&proj[(size_t)nqg * PROJW + h * 16 + c4];
            *(uint2*)&qfrag[q * 40 + c4] =
                make_uint2(pk2(f2bf(S1 * v.x), f2bf(S1 * v.y)),
                           pk2(f2bf(S1 * v.z), f2bf(S1 * v.w)));
            qfrag[q * 40 + 28 + (t & 3)] = 0;
        }
        if (t < 96) {
            int q = t / 3, c4 = (t % 3) * 4;
            int nqg = b * Nv + blk * BQv + q;
            float4 v = *(const float4*)&qpts[(size_t)nqg * QPD + h * 12 + c4];
            *(uint2*)&qfrag[q * 40 + 16 + c4] =
                make_uint2(pk2(f2bf(hw * v.x), f2bf(hw * v.y)),
                           pk2(f2bf(hw * v.z), f2bf(hw * v.w)));
        }
        if (t < 32) {
            int nqg = b * Nv + blk * BQv + t;
            rowb[t] = -0.5f * hw * qsq[(size_t)nqg * Hv + t >= 0 ? (size_t)nqg * Hv + h - ((size_t)nqg * Hv + h) + (size_t)nqg * Hv + h : 0];
            rowb[t] = -0.5f * hw * qsq[(size_t)nqg * Hv + h];
            qmL[t] = smask[nqg];
        }
        // V channels (c 0..15), transposed store
        {
            int k = t >> 2, c0 = (t & 3) << 2;
            int g = nkgL[k];
            float4 v = (g >= 0) ? *(const float4*)&proj[(size_t)g * PROJW + 384 + h * 16 + c0]
                                : make_float4(0, 0, 0, 0);
            vtileT[(c0 + 0) * 136 + k] = f2bf(v.x);
            vtileT[(c0 + 1) * 136 + k] = f2bf(v.y);
            vtileT[(c0 + 2) * 136 + k] = f2bf(v.z);
            vtileT[(c0 + 3) * 136 + k] = f2bf(v.w);
        }
        // V points (c 16..39), transposed store
        for (int i = t; i < 768; i += 512) {
            int k = i / 6, p = i % 6;
            int g = nkgL[k];
            float4 v = (g >= 0) ? *(const float4*)&vpts[(size_t)g * (Hv * PVv * 3) + h * 24 + p * 4]
                                : make_float4(0, 0, 0, 0);
            int c0 = 16 + p * 4;
            vtileT[(c0 + 0) * 136 + k] = f2bf(v.x);
            vtileT[(c0 + 1) * 136 + k] = f2bf(v.y);
            vtileT[(c0 + 2) * 136 + k] = f2bf(v.z);
            vtileT[(c0 + 3) * 136 + k] = f2bf(v.w);
        }
        __syncthreads();

        // ---- logits MFMA ----
        f32x4 d[2];
        d[0] = 0; d[1] = 0;
        {
            bf16x8 bfr = *(const bf16x8*)&kfrag[(wv * 16 + lr) * 40 + quad * 8];
            bf16x8 a0 = *(const bf16x8*)&qfrag[lr * 40 + quad * 8];
            bf16x8 a1 = *(const bf16x8*)&qfrag[(16 + lr) * 40 + quad * 8];
            d[0] = __builtin_amdgcn_mfma_f32_16x16x32_bf16(a0, bfr, d[0], 0, 0, 0);
            d[1] = __builtin_amdgcn_mfma_f32_16x16x32_bf16(a1, bfr, d[1], 0, 0, 0);
        }
        {
            const short* bb = bbias2 + (size_t)(bblk * 12 + h) * 4096;
            #pragma unroll
            for (int mt = 0; mt < 2; ++mt) {
                #pragma unroll
                for (int r = 0; r < 4; ++r) {
                    int q = mt * 16 + quad * 4 + r;
                    int k = wv * 16 + lr;
                    float logit = d[mt][r] + rowb[q] + colb[k]
                                + 1e5f * (qmL[q] * kmL[k] - 1.f)
                                + bf2f(bb[q * 128 + k]);
                    sc[q * 132 + k] = logit;
                }
            }
        }
        __syncthreads();

        // ---- softmax ----
        {
            int q = t >> 4, i0 = (t & 15) * 8;
            float v[8];
            float m = -3.0e38f;
            #pragma unroll
            for (int j = 0; j < 8; ++j) { v[j] = sc[q * 132 + i0 + j]; m = fmaxf(m, v[j]); }
            #pragma unroll
            for (int off = 1; off <= 8; off <<= 1) m = fmaxf(m, __shfl_xor(m, off, 64));
            float ssum = 0.f;
            #pragma unroll
            for (int j = 0; j < 8; ++j) { v[j] = __expf(v[j] - m); ssum += v[j]; }
            #pragma unroll
            for (int off = 1; off <= 8; off <<= 1) ssum += __shfl_xor(ssum, off, 64);
            float inv = 1.f / ssum;
            short a8[8];
            #pragma unroll
            for (int j = 0; j < 8; ++j) a8[j] = f2bf(v[j] * inv);
            uint4 packed = make_uint4(pk2(a8[0], a8[1]), pk2(a8[2], a8[3]),
                                      pk2(a8[4], a8[5]), pk2(a8[6], a8[7]));
            *(uint4*)&Abuf[q * 136 + i0] = packed;
            *(uint4*)&Aws[((size_t)(bblk * 32 + q) * 12 + h) * 128 + i0] = packed;
        }
        __syncthreads();

        // ---- AV MFMA (b128 LDS reads from transposed V) ----
        if (wv < 6) {
            int mt = wv & 1, nt = wv >> 1;
            f32x4 acc = 0;
            #pragma unroll
            for (int kt = 0; kt < 4; ++kt) {
                bf16x8 a = *(const bf16x8*)&Abuf[(mt * 16 + lr) * 136 + quad * 8 + kt * 32];
                bf16x8 bv = *(const bf16x8*)&vtileT[(nt * 16 + lr) * 136 + quad * 8 + kt * 32];
                acc = __builtin_amdgcn_mfma_f32_16x16x32_bf16(a, bv, acc, 0, 0, 0);
            }
            int c = nt * 16 + lr;
            #pragma unroll
            for (int r = 0; r < 4; ++r) {
                int q = mt * 16 + quad * 4 + r;
                size_t nqg = (size_t)b * Nv + blk * BQv + q;
                if (c < 16) feats[nqg * FEAT + h * 16 + c] = acc[r];
                else if (c < 40) optraw[nqg * 288 + h * 24 + (c - 16)] = acc[r];
            }
        }
        __syncthreads();
    }
}

// ---------------- K5b: o_pair + rotation + feats (operands direct from global) ----------------
__global__ __launch_bounds__(64) void k_pair(const short* __restrict__ Aws,
                                             const short* __restrict__ pairzT,
                                             const float* __restrict__ optraw,
                                             const float* __restrict__ rots,
                                             const float* __restrict__ trans,
                                             float* __restrict__ feats) {
    __shared__ float Rt[12];
    int t = threadIdx.x;
    int bid = blockIdx.x;          // == nqg
    int lr = t & 15, quad = t >> 4;

    if (t < 9) Rt[t] = rots[(size_t)bid * 9 + t];
    if (t < 3) Rt[9 + t] = trans[(size_t)bid * 3 + t];
    __syncthreads();

    const short* Ab = Aws + (size_t)bid * 1536;       // 12 heads x 128
    const short* Pb = pairzT + (size_t)bid * 4096;    // 32 cols x 128
    f32x4 acc0 = 0, acc1 = 0;
    #pragma unroll
    for (int kt = 0; kt < 4; ++kt) {
        int ko = kt * 32 + quad * 8;
        bf16x8 a = 0;
        if (lr < 12) a = *(const bf16x8*)&Ab[lr * 128 + ko];
        bf16x8 b0 = *(const bf16x8*)&Pb[lr * 128 + ko];
        bf16x8 b1 = *(const bf16x8*)&Pb[(16 + lr) * 128 + ko];
        acc0 = __builtin_amdgcn_mfma_f32_16x16x32_bf16(a, b0, acc0, 0, 0, 0);
        acc1 = __builtin_amdgcn_mfma_f32_16x16x32_bf16(a, b1, acc1, 0, 0, 0);
    }
    float* frow = feats + (size_t)bid * FEAT;
    #pragma unroll
    for (int r = 0; r < 4; ++r) {
        int hh = quad * 4 + r;
        if (hh < 12) {
            frow[576 + hh * 32 + lr] = acc0[r];
            frow[576 + hh * 32 + 16 + lr] = acc1[r];
        }
    }

    for (int p = t; p < 96; p += 64) {
        float x = optraw[(size_t)bid * 288 + p * 3 + 0] - Rt[9];
        float y = optraw[(size_t)bid * 288 + p * 3 + 1] - Rt[10];
        float z = optraw[(size_t)bid * 288 + p * 3 + 2] - Rt[11];
        float lx = Rt[0] * x + Rt[3] * y + Rt[6] * z;
        float ly = Rt[1] * x + Rt[4] * y + Rt[7] * z;
        float lz = Rt[2] * x + Rt[5] * y + Rt[8] * z;
        frow[192 + p * 3 + 0] = lx;
        frow[192 + p * 3 + 1] = ly;
        frow[192 + p * 3 + 2] = lz;
        frow[480 + p] = sqrtf(lx * lx + ly * ly + lz * lz + 1e-8f);
    }
}

// ---------------- K6: out = feats @ Wout^T (4096x960x384) ----------------
__global__ __launch_bounds__(256) void k_out(const float* __restrict__ A,
                                             const float* __restrict__ Wo,
                                             float* __restrict__ C) {
    __shared__ float As[32][65];
    __shared__ float Bs[32][65];
    int t = threadIdx.x;
    int m0 = blockIdx.x * 64;
    int c0 = blockIdx.y * 64;
    int tx = t & 15, ty = t >> 4;
    int lr = t >> 2, lk = (t & 3) * 8;
    float acc[4][4] = {};
    for (int k0 = 0; k0 < FEAT; k0 += 32) {
        const float4* ap = (const float4*)(A + (size_t)(m0 + lr) * FEAT + k0 + lk);
        const float4* bp = (const float4*)(Wo + (size_t)(c0 + lr) * FEAT + k0 + lk);
        float4 a0 = ap[0], a1 = ap[1];
        float4 b0 = bp[0], b1 = bp[1];
        As[lk + 0][lr] = a0.x; As[lk + 1][lr] = a0.y; As[lk + 2][lr] = a0.z; As[lk + 3][lr] = a0.w;
        As[lk + 4][lr] = a1.x; As[lk + 5][lr] = a1.y; As[lk + 6][lr] = a1.z; As[lk + 7][lr] = a1.w;
        Bs[lk + 0][lr] = b0.x; Bs[lk + 1][lr] = b0.y; Bs[lk + 2][lr] = b0.z; Bs[lk + 3][lr] = b0.w;
        Bs[lk + 4][lr] = b1.x; Bs[lk + 5][lr] = b1.y; Bs[lk + 6][lr] = b1.z; Bs[lk + 7][lr] = b1.w;
        __syncthreads();
        #pragma unroll
        for (int kk = 0; kk < 32; ++kk) {
            float a4[4], b4[4];
            #pragma unroll
            for (int i = 0; i < 4; ++i) a4[i] = As[kk][ty * 4 + i];
            #pragma unroll
            for (int j = 0; j < 4; ++j) b4[j] = Bs[kk][tx * 4 + j];
            #pragma unroll
            for (int i = 0; i < 4; ++i)
                #pragma unroll
                for (int j = 0; j < 4; ++j) acc[i][j] += a4[i] * b4[j];
        }
        __syncthreads();
    }
    #pragma unroll
    for (int i = 0; i < 4; ++i)
        #pragma unroll
        for (int j = 0; j < 4; ++j)
            C[(size_t)(m0 + ty * 4 + i) * CSv + c0 + tx * 4 + j] = acc[i][j];
}

// ---------------- launch ----------------
extern "C" void kernel_launch(void* const* d_in, const int* in_sizes, int n_in,
                              void* d_out, int out_size, void* d_ws, size_t ws_size,
                              hipStream_t stream) {
    const float* s          = (const float*)d_in[0];
    const float* cond       = (const float*)d_in[1];
    const float* z          = (const float*)d_in[2];
    const float* trans      = (const float*)d_in[3];
    const float* rots       = (const float*)d_in[4];
    const float* smask      = (const float*)d_in[5];
    const int*   cidx       = (const int*)d_in[6];
    const float* ln_cond_w  = (const float*)d_in[7];
    const float* lin_cond_W = (const float*)d_in[8];
    const float* lin_cond_b = (const float*)d_in[9];
    const float* lin_cond_nb_W = (const float*)d_in[10];
    const float* ln_z_w     = (const float*)d_in[11];
    const float* ln_z_b     = (const float*)d_in[12];
    const float* Wq         = (const float*)d_in[13];
    const float* Wk         = (const float*)d_in[14];
    const float* Wv         = (const float*)d_in[15];
    const float* Wqp        = (const float*)d_in[16];
    const float* Wkvp       = (const float*)d_in[17];
    const float* Wb         = (const float*)d_in[18];
    const float* Wdz        = (const float*)d_in[19];
    const float* head_w     = (const float*)d_in[20];
    const float* Wout       = (const float*)d_in[21];
    float* out = (float*)d_out;

    float* p = (float*)d_ws;
    short* wp = (short*)p; p += 3072;
    float* SBp = p; p += 96;
    short* wsW  = (short*)p; p += 221184;   // 1152*384 bf16
    short* wsW2 = (short*)p; p += 98304;    // 768*256 bf16
    short* cnbf = (short*)p; p += 65536;    // 512*256 bf16
    float* gb   = p; p += (size_t)512 * 768;
    short* s2bf = (short*)p; p += (size_t)Bv * Nv * CSv / 2;
    float* proj = p; p += (size_t)Bv * Nv * PROJW;
    float* qpts = p; p += (size_t)Bv * Nv * QPD;
    float* kpts = p; p += (size_t)Bv * Nv * QPD;
    float* vpts = p; p += (size_t)Bv * Nv * (Hv * PVv * 3);
    float* qsq  = p; p += (size_t)Bv * Nv * Hv;
    float* ksq  = p; p += (size_t)Bv * Nv * Hv;
    short* bbias2 = (short*)p; p += (size_t)128 * 12 * 4096 / 2;   // bf16 now
    short* pairzT = (short*)p; p += (size_t)128 * 32 * 32 * 64;
    short* Aws    = (short*)p; p += (size_t)4096 * 12 * 64;
    float* optraw = p; p += (size_t)4096 * 288;
    float* feats  = p; p += (size_t)Bv * Nv * FEAT;

    k_wcvt<<<624, 256, 0, stream>>>(Wq, Wk, Wv, Wqp, Wkvp, lin_cond_W, lin_cond_nb_W,
                                    wsW, wsW2);
    k_prep<<<1, 256, 0, stream>>>(Wb, Wdz, ln_z_w, ln_z_b, wp, SBp);
    k_condln<<<Bv * NCv, 256, 0, stream>>>(cond, ln_cond_w, cnbf);
    k_gemm_bt<<<dim3(4, 6), 256, 0, stream>>>(cnbf, wsW2, gb, CCONDv, 768);
    k_s2<<<Bv * Nv, 128, 0, stream>>>(s, gb, lin_cond_b, cidx, smask, s2bf);
    k_gemm_bt<<<dim3(32, 9), 256, 0, stream>>>(s2bf, wsW, proj, CSv, PROJW);
    k_post<<<Bv * Nv, 192, 0, stream>>>(proj, rots, trans, qpts, kpts, vpts, qsq, ksq);
    k_zproj2<<<Bv * NBLKv * BQv, 256, 0, stream>>>(z, wp, SBp, bbias2, pairzT);
    k_attn_main<<<Bv * NBLKv * 6, 512, 0, stream>>>(proj, qpts, kpts, vpts, qsq, ksq,
                                                    bbias2, smask, head_w, Aws, optraw, feats);
    k_pair<<<Bv * NBLKv * BQv, 64, 0, stream>>>(Aws, pairzT, optraw, rots, trans, feats);
    k_out<<<dim3(64, 6), 256, 0, stream>>>(feats, Wout, out);
}

// Round 2
// 580.327 us; speedup vs baseline: 1.1211x; 1.0629x over previous
//
#include <hip/hip_runtime.h>
#include <math.h>

// ---------------- constants ----------------
constexpr int Bv = 2, Nv = 2048, NCv = 256;
constexpr int CSv = 384, CCONDv = 256;
constexpr int CHv = 16, Hv = 12, PQKv = 4, PVv = 8;
constexpr int BQv = 32, BKv = 128, NBLKv = 64;
constexpr int HC = Hv * CHv;               // 192
constexpr int QPD = Hv * PQKv * 3;         // 144
constexpr int FEAT = 960;                  // H*CONCAT
constexpr int PROJW = 1152;                // q(192)+k(192)+v(192)+qp(144)+kvp(432)
constexpr int NPAD = 2144;                 // 48 + 2048 + 48 padded n-axis
constexpr float S1 = 0.14433756729740643f; // sqrt(1/48)
constexpr float S2 = 0.5773502691896258f;  // sqrt(1/3)
constexpr float HWS = 0.13608276348795434f;// sqrt(1/54)

typedef __attribute__((ext_vector_type(8))) short bf16x8;
typedef __attribute__((ext_vector_type(4))) float f32x4;

__device__ __forceinline__ short f2bf(float f) {
    unsigned u = __float_as_uint(f);
    u += 0x7FFF + ((u >> 16) & 1);
    return (short)(u >> 16);
}
__device__ __forceinline__ float bf2f(short s) {
    return __uint_as_float(((unsigned)(unsigned short)s) << 16);
}
__device__ __forceinline__ unsigned pk2(short lo, short hi) {
    return ((unsigned)(unsigned short)lo) | (((unsigned)(unsigned short)hi) << 16);
}

union BF8 { short s[8]; bf16x8 v; uint4 u; };

// ---------------- helpers ----------------
__device__ __forceinline__ float blockReduceSum(float v, volatile float* red, int t, int nthr) {
    #pragma unroll
    for (int off = 32; off > 0; off >>= 1) v += __shfl_down(v, off, 64);
    int wid = t >> 6, lane = t & 63, nw = nthr >> 6;
    __syncthreads();
    if (lane == 0) red[wid] = v;
    __syncthreads();
    float r = 0.f;
    for (int w = 0; w < nw; ++w) r += red[w];
    return r;
}

// ---------------- K0: merged head kernel: wcvt + prep + condln ----------------
// blocks 0..623: weight bf16 convert; block 624: z-proj weight fold; 625..1136: LN(cond)
__global__ __launch_bounds__(256) void k_head(const float* __restrict__ Wq,
                                              const float* __restrict__ Wk,
                                              const float* __restrict__ Wv,
                                              const float* __restrict__ Wqp,
                                              const float* __restrict__ Wkvp,
                                              const float* __restrict__ Wg,
                                              const float* __restrict__ Wnb,
                                              short* __restrict__ wsW,
                                              short* __restrict__ wsW2,
                                              const float* __restrict__ Wb,
                                              const float* __restrict__ Wdz,
                                              const float* __restrict__ lnzw,
                                              const float* __restrict__ lnzb,
                                              short* __restrict__ wp,
                                              float* __restrict__ SB,
                                              const float* __restrict__ cond,
                                              const float* __restrict__ lncw,
                                              short* __restrict__ cnbf) {
    __shared__ float red[4];
    int bid = blockIdx.x;
    int t = threadIdx.x;
    if (bid < 624) {
        int off = (bid * 256 + t) * 4;
        const float* src;
        int rel;
        if (off < 442368) {
            rel = off;
            if (rel < 73728) src = Wq;
            else if (rel < 147456) { src = Wk; rel -= 73728; }
            else if (rel < 221184) { src = Wv; rel -= 147456; }
            else if (rel < 276480) { src = Wqp; rel -= 221184; }
            else { src = Wkvp; rel -= 276480; }
            float4 v = *(const float4*)(src + rel);
            *(uint2*)(wsW + off) = make_uint2(pk2(f2bf(v.x), f2bf(v.y)), pk2(f2bf(v.z), f2bf(v.w)));
        } else {
            int o2 = off - 442368;
            rel = o2;
            if (rel < 98304) src = Wg; else { src = Wnb; rel -= 98304; }
            float4 v = *(const float4*)(src + rel);
            *(uint2*)(wsW2 + o2) = make_uint2(pk2(f2bf(v.x), f2bf(v.y)), pk2(f2bf(v.z), f2bf(v.w)));
        }
    } else if (bid == 624) {
        if (t < 176) {
            int c = t >> 2, q = t & 3;
            const float* wrow = (c < 12) ? (Wb + (size_t)c * 128) : (Wdz + (size_t)(c - 12) * 128);
            float sacc = 0.f, bacc = 0.f;
            for (int i = q * 32; i < q * 32 + 32; ++i) {
                float wf = wrow[i] * lnzw[i];
                short bs = f2bf(wf);
                wp[c * 128 + i] = bs;
                sacc += bf2f(bs);
                bacc += lnzb[i] * wrow[i];
            }
            sacc += __shfl_xor(sacc, 1, 64); sacc += __shfl_xor(sacc, 2, 64);
            bacc += __shfl_xor(bacc, 1, 64); bacc += __shfl_xor(bacc, 2, 64);
            if (q == 0) { SB[c] = sacc; SB[48 + c] = bacc; }
        }
        for (int i = t; i < 512; i += 256) wp[44 * 128 + i] = 0;
        if (t >= 176 && t < 180) { SB[t - 132] = 0.f; SB[48 + t - 132] = 0.f; }
    } else {
        int row = bid - 625;
        float c = cond[row * CCONDv + t];
        float mu = blockReduceSum(c, red, t, 256) * (1.f / CCONDv);
        float d = c - mu;
        float var = blockReduceSum(d * d, red, t, 256) * (1.f / CCONDv);
        cnbf[row * CCONDv + t] = f2bf(d * rsqrtf(var + 1e-5f) * lncw[t]);
    }
}

// ---------------- generic bf16 GEMM: C[m][n] = sum_k A[m][k]*B[n][k] ----------------
__global__ __launch_bounds__(256) void k_gemm_bt(const short* __restrict__ A,
                                                 const short* __restrict__ B,
                                                 float* __restrict__ C,
                                                 int K, int ldc) {
    __shared__ short As[128 * 40];
    __shared__ short Bs[128 * 40];
    int t = threadIdx.x;
    int m0 = blockIdx.x * 128, n0 = blockIdx.y * 128;
    int wv = t >> 6, lane = t & 63, lr = lane & 15, quad = lane >> 4;
    int mq = (wv & 1) * 64, nq = (wv >> 1) * 64;
    f32x4 acc[4][4];
    #pragma unroll
    for (int i = 0; i < 4; ++i)
        #pragma unroll
        for (int j = 0; j < 4; ++j) acc[i][j] = 0;

    int r0 = t >> 2, c8 = (t & 3) * 8;
    int r1 = (t + 256) >> 2, c81 = ((t + 256) & 3) * 8;

    for (int k0 = 0; k0 < K; k0 += 32) {
        uint4 a0 = *(const uint4*)(A + (size_t)(m0 + r0) * K + k0 + c8);
        uint4 a1 = *(const uint4*)(A + (size_t)(m0 + r1) * K + k0 + c81);
        uint4 b0 = *(const uint4*)(B + (size_t)(n0 + r0) * K + k0 + c8);
        uint4 b1 = *(const uint4*)(B + (size_t)(n0 + r1) * K + k0 + c81);
        *(uint4*)&As[r0 * 40 + c8] = a0;
        *(uint4*)&As[r1 * 40 + c81] = a1;
        *(uint4*)&Bs[r0 * 40 + c8] = b0;
        *(uint4*)&Bs[r1 * 40 + c81] = b1;
        __syncthreads();
        bf16x8 af[4], bf[4];
        #pragma unroll
        for (int i = 0; i < 4; ++i) {
            af[i] = *(const bf16x8*)&As[(mq + i * 16 + lr) * 40 + quad * 8];
            bf[i] = *(const bf16x8*)&Bs[(nq + i * 16 + lr) * 40 + quad * 8];
        }
        #pragma unroll
        for (int i = 0; i < 4; ++i)
            #pragma unroll
            for (int j = 0; j < 4; ++j)
                acc[i][j] = __builtin_amdgcn_mfma_f32_16x16x32_bf16(af[i], bf[j], acc[i][j], 0, 0, 0);
        __syncthreads();
    }
    #pragma unroll
    for (int i = 0; i < 4; ++i) {
        #pragma unroll
        for (int j = 0; j < 4; ++j) {
            int col = n0 + nq + j * 16 + lr;
            #pragma unroll
            for (int r = 0; r < 4; ++r) {
                int row = m0 + mq + i * 16 + quad * 4 + r;
                C[(size_t)row * ldc + col] = acc[i][j][r];
            }
        }
    }
}

// ---------------- K2: LN(s) + gather gate/bias -> s2 (bf16) ----------------
__global__ __launch_bounds__(128) void k_s2(const float* __restrict__ s,
                                            const float* __restrict__ gb,
                                            const float* __restrict__ bg,
                                            const int* __restrict__ cidx,
                                            const float* __restrict__ smask,
                                            short* __restrict__ s2bf) {
    __shared__ float red[4];
    int row = blockIdx.x;
    int t = threadIdx.x;
    const float* sr = s + (size_t)row * CSv;
    float x0 = sr[t], x1 = sr[t + 128], x2 = sr[t + 256];
    float mu = blockReduceSum(x0 + x1 + x2, red, t, 128) * (1.f / CSv);
    float d0 = x0 - mu, d1 = x1 - mu, d2 = x2 - mu;
    float var = blockReduceSum(d0 * d0 + d1 * d1 + d2 * d2, red, t, 128) * (1.f / CSv);
    float rs = rsqrtf(var + 1e-5f);
    int b = row / Nv;
    int ci = cidx[row];
    float m = smask[row];
    const float* gbr = gb + (size_t)(b * NCv + ci) * 768;
    float dd[3] = {d0, d1, d2};
    #pragma unroll
    for (int j = 0; j < 3; ++j) {
        int cc = t + j * 128;
        float sn = dd[j] * rs;
        float g = (gbr[cc] + bg[cc]) * m, bi = gbr[384 + cc] * m;
        s2bf[(size_t)row * CSv + cc] = f2bf(sn * (1.f / (1.f + expf(-g))) + bi);
    }
}

// ---------------- K3b: point rotation + qsq/ksq from proj ----------------
__global__ __launch_bounds__(192) void k_post(const float* __restrict__ proj,
                                              const float* __restrict__ rots,
                                              const float* __restrict__ trans,
                                              float* __restrict__ qpts,
                                              float* __restrict__ kpts,
                                              float* __restrict__ vpts,
                                              float* __restrict__ qsq,
                                              float* __restrict__ ksq) {
    __shared__ float R[9], tr[3];
    int row = blockIdx.x;
    int t = threadIdx.x;
    if (t < 9) R[t] = rots[(size_t)row * 9 + t];
    if (t < 3) tr[t] = trans[(size_t)row * 3 + t];
    __syncthreads();
    const float* pr = proj + (size_t)row * PROJW + 576;
    float x = pr[t * 3 + 0], y = pr[t * 3 + 1], z = pr[t * 3 + 2];
    float ox = R[0] * x + R[1] * y + R[2] * z + tr[0];
    float oy = R[3] * x + R[4] * y + R[5] * z + tr[1];
    float oz = R[6] * x + R[7] * y + R[8] * z + tr[2];
    float sq = ox * ox + oy * oy + oz * oz;
    if (t < 48) {
        qpts[(size_t)row * QPD + t * 3 + 0] = ox;
        qpts[(size_t)row * QPD + t * 3 + 1] = oy;
        qpts[(size_t)row * QPD + t * 3 + 2] = oz;
        float s4 = sq + __shfl_xor(sq, 1, 64);
        s4 += __shfl_xor(s4, 2, 64);
        if ((t & 3) == 0) qsq[(size_t)row * Hv + (t >> 2)] = s4;
    } else {
        int p = t - 48;
        int h = p / 12, pp = p % 12;
        if (pp < PQKv) {
            kpts[(size_t)row * QPD + (h * PQKv + pp) * 3 + 0] = ox;
            kpts[(size_t)row * QPD + (h * PQKv + pp) * 3 + 1] = oy;
            kpts[(size_t)row * QPD + (h * PQKv + pp) * 3 + 2] = oz;
            float s4 = sq + __shfl_xor(sq, 1, 64);
            s4 += __shfl_xor(s4, 2, 64);
            if (pp == 0) ksq[(size_t)row * Hv + h] = s4;
        } else {
            int vi = h * PVv + pp - PQKv;
            vpts[(size_t)row * (Hv * PVv * 3) + vi * 3 + 0] = ox;
            vpts[(size_t)row * (Hv * PVv * 3) + vi * 3 + 1] = oy;
            vpts[(size_t)row * (Hv * PVv * 3) + vi * 3 + 2] = oz;
        }
    }
}

// ---------------- K4: merged zproj (blocks 0..4095) + cond GEMM (4096..4119) ----------------
__global__ __launch_bounds__(256) void k_zg(const float* __restrict__ z,
                                            const short* __restrict__ wp,
                                            const float* __restrict__ SB,
                                            short* __restrict__ bbias2,
                                            short* __restrict__ pairzT,
                                            const short* __restrict__ cnbf,
                                            const short* __restrict__ wsW2,
                                            float* __restrict__ gb) {
    extern __shared__ char smem[];
    int t = threadIdx.x;
    int bid = blockIdx.x;
    if (bid >= 4096) {
        // ---- cond gemm: 128x128 tile, A=cnbf (512x256), B=wsW2 (768x256), C=gb ----
        short* As = (short*)smem;
        short* Bs = As + 128 * 40;
        int g = bid - 4096;
        int m0 = (g & 3) * 128, n0 = (g >> 2) * 128;
        const int K = CCONDv, ldc = 768;
        int wv = t >> 6, lane = t & 63, lr = lane & 15, quad = lane >> 4;
        int mq = (wv & 1) * 64, nq = (wv >> 1) * 64;
        f32x4 acc[4][4];
        #pragma unroll
        for (int i = 0; i < 4; ++i)
            #pragma unroll
            for (int j = 0; j < 4; ++j) acc[i][j] = 0;
        int r0 = t >> 2, c8 = (t & 3) * 8;
        int r1 = (t + 256) >> 2, c81 = ((t + 256) & 3) * 8;
        for (int k0 = 0; k0 < K; k0 += 32) {
            uint4 a0 = *(const uint4*)(cnbf + (size_t)(m0 + r0) * K + k0 + c8);
            uint4 a1 = *(const uint4*)(cnbf + (size_t)(m0 + r1) * K + k0 + c81);
            uint4 b0 = *(const uint4*)(wsW2 + (size_t)(n0 + r0) * K + k0 + c8);
            uint4 b1 = *(const uint4*)(wsW2 + (size_t)(n0 + r1) * K + k0 + c81);
            *(uint4*)&As[r0 * 40 + c8] = a0;
            *(uint4*)&As[r1 * 40 + c81] = a1;
            *(uint4*)&Bs[r0 * 40 + c8] = b0;
            *(uint4*)&Bs[r1 * 40 + c81] = b1;
            __syncthreads();
            bf16x8 af[4], bf[4];
            #pragma unroll
            for (int i = 0; i < 4; ++i) {
                af[i] = *(const bf16x8*)&As[(mq + i * 16 + lr) * 40 + quad * 8];
                bf[i] = *(const bf16x8*)&Bs[(nq + i * 16 + lr) * 40 + quad * 8];
            }
            #pragma unroll
            for (int i = 0; i < 4; ++i)
                #pragma unroll
                for (int j = 0; j < 4; ++j)
                    acc[i][j] = __builtin_amdgcn_mfma_f32_16x16x32_bf16(af[i], bf[j], acc[i][j], 0, 0, 0);
            __syncthreads();
        }
        #pragma unroll
        for (int i = 0; i < 4; ++i)
            #pragma unroll
            for (int j = 0; j < 4; ++j) {
                int col = n0 + nq + j * 16 + lr;
                #pragma unroll
                for (int r = 0; r < 4; ++r) {
                    int row = m0 + mq + i * 16 + quad * 4 + r;
                    gb[(size_t)row * ldc + col] = acc[i][j][r];
                }
            }
        return;
    }
    // ---- zproj path ----
    short* zbuf = (short*)smem;                 // 128*136
    short* wbuf = zbuf + 128 * 136;             // 48*136
    float* muL  = (float*)(wbuf + 48 * 136);    // 128
    float* rsL  = muL + 128;                    // 128
    float* SL   = rsL + 128;                    // 48
    float* BL   = SL + 48;                      // 48

    int bblk = bid >> 5, qq = bid & 31;
    size_t row0 = (size_t)bid * 128;

    for (int idx = t; idx < 768; idx += 256) {
        int c = idx >> 4, k8 = idx & 15;
        uint4 v = *(const uint4*)(wp + c * 128 + k8 * 8);
        *(uint4*)&wbuf[c * 136 + k8 * 8] = v;
    }
    if (t < 96) {
        float v = SB[t];
        if (t < 48) SL[t] = v; else BL[t - 48] = v;
    }

    const float4* zsrc = (const float4*)(z + row0 * 128);
    #pragma unroll
    for (int it = 0; it < 16; ++it) {
        int f = it * 256 + t;
        int r = f >> 5, c4 = f & 31;
        float4 v = zsrc[f];
        short s0 = f2bf(v.x), s1 = f2bf(v.y), s2v = f2bf(v.z), s3 = f2bf(v.w);
        *(uint2*)&zbuf[r * 136 + c4 * 4] = make_uint2(pk2(s0, s1), pk2(s2v, s3));
        float sm = v.x + v.y + v.z + v.w;
        float sq = v.x * v.x + v.y * v.y + v.z * v.z + v.w * v.w;
        #pragma unroll
        for (int off = 1; off <= 16; off <<= 1) {
            sm += __shfl_xor(sm, off, 64);
            sq += __shfl_xor(sq, off, 64);
        }
        if ((t & 31) == 0) {
            float mu = sm * (1.f / 128.f);
            float var = sq * (1.f / 128.f) - mu * mu;
            muL[r] = mu;
            rsL[r] = rsqrtf(var + 1e-5f);
        }
    }
    __syncthreads();

    int wv = t >> 6, lane = t & 63;
    int lr = lane & 15, quad = lane >> 4;
    int mb = wv * 32;
    f32x4 acc[2][3];
    #pragma unroll
    for (int i = 0; i < 2; ++i)
        #pragma unroll
        for (int j = 0; j < 3; ++j) acc[i][j] = 0;
    #pragma unroll
    for (int kt = 0; kt < 4; ++kt) {
        int ko = kt * 32 + quad * 8;
        bf16x8 a0 = *(const bf16x8*)&zbuf[(mb + lr) * 136 + ko];
        bf16x8 a1 = *(const bf16x8*)&zbuf[(mb + 16 + lr) * 136 + ko];
        bf16x8 b0 = *(const bf16x8*)&wbuf[lr * 136 + ko];
        bf16x8 b1 = *(const bf16x8*)&wbuf[(16 + lr) * 136 + ko];
        bf16x8 b2 = *(const bf16x8*)&wbuf[(32 + lr) * 136 + ko];
        acc[0][0] = __builtin_amdgcn_mfma_f32_16x16x32_bf16(a0, b0, acc[0][0], 0, 0, 0);
        acc[0][1] = __builtin_amdgcn_mfma_f32_16x16x32_bf16(a0, b1, acc[0][1], 0, 0, 0);
        acc[0][2] = __builtin_amdgcn_mfma_f32_16x16x32_bf16(a0, b2, acc[0][2], 0, 0, 0);
        acc[1][0] = __builtin_amdgcn_mfma_f32_16x16x32_bf16(a1, b0, acc[1][0], 0, 0, 0);
        acc[1][1] = __builtin_amdgcn_mfma_f32_16x16x32_bf16(a1, b1, acc[1][1], 0, 0, 0);
        acc[1][2] = __builtin_amdgcn_mfma_f32_16x16x32_bf16(a1, b2, acc[1][2], 0, 0, 0);
    }

    short* bb_base = bbias2 + (size_t)(bblk * 12) * 4096 + qq * 128;
    short* pz_base = pairzT + (size_t)bid * 32 * 128;
    #pragma unroll
    for (int mt = 0; mt < 2; ++mt) {
        #pragma unroll
        for (int nt = 0; nt < 3; ++nt) {
            int col = nt * 16 + lr;
            int kbase = mb + mt * 16 + quad * 4;
            float ov[4];
            #pragma unroll
            for (int r4 = 0; r4 < 4; ++r4) {
                int rl = kbase + r4;
                ov[r4] = rsL[rl] * (acc[mt][nt][r4] - muL[rl] * SL[col]) + BL[col];
            }
            if (col < 12) {
                *(uint2*)&bb_base[(size_t)col * 4096 + kbase] =
                    make_uint2(pk2(f2bf(S2 * ov[0]), f2bf(S2 * ov[1])),
                               pk2(f2bf(S2 * ov[2]), f2bf(S2 * ov[3])));
            } else if (col < 44) {
                int c = col - 12;
                *(uint2*)&pz_base[c * 128 + kbase] =
                    make_uint2(pk2(f2bf(ov[0]), f2bf(ov[1])), pk2(f2bf(ov[2]), f2bf(ov[3])));
            }
        }
    }
}

// ---------------- K4c: bf16 K/Q/V operand cache (padded, pre-scaled, V transposed) ----------------
// grid = B*12*17 blocks x 256 thr; tile = 128 padded indices.
__global__ __launch_bounds__(256) void k_kvcache(const float* __restrict__ proj,
                                                 const float* __restrict__ qpts,
                                                 const float* __restrict__ kpts,
                                                 const float* __restrict__ vpts,
                                                 const float* __restrict__ qsq,
                                                 const float* __restrict__ ksq,
                                                 const float* __restrict__ smask,
                                                 const float* __restrict__ head_w,
                                                 short* __restrict__ kc,
                                                 short* __restrict__ qc,
                                                 short* __restrict__ vTc,
                                                 float* __restrict__ cb,
                                                 float* __restrict__ rb,
                                                 float* __restrict__ kmp) {
    __shared__ short vt[40 * 136];
    int t = threadIdx.x;
    int tile = blockIdx.x % 17;
    int bh = blockIdx.x / 17;
    int b = bh / 12, h = bh % 12;
    float hw = log1pf(expf(head_w[h])) * HWS;
    int pn0 = tile * 128;
    int npn = (pn0 + 128 <= NPAD) ? 128 : (NPAD - pn0);   // 96 on last tile

    // ---- kc rows (K-frag: 16 ch + 12 pts + 4 zero), clamped ----
    for (int i = t; i < npn * 4; i += 256) {
        int r = i >> 2, q = i & 3;
        int pn = pn0 + r;
        int n = pn - 48; n = n < 0 ? 0 : (n > Nv - 1 ? Nv - 1 : n);
        size_t g = (size_t)b * Nv + n;
        BF8 o;
        if (q < 2) {
            const float* src = proj + g * PROJW + 192 + h * 16 + q * 8;
            #pragma unroll
            for (int j = 0; j < 8; ++j) o.s[j] = f2bf(src[j]);
        } else if (q == 2) {
            const float* src = kpts + g * QPD + h * 12;
            #pragma unroll
            for (int j = 0; j < 8; ++j) o.s[j] = f2bf(src[j]);
        } else {
            const float* src = kpts + g * QPD + h * 12 + 8;
            #pragma unroll
            for (int j = 0; j < 4; ++j) o.s[j] = f2bf(src[j]);
            o.s[4] = o.s[5] = o.s[6] = o.s[7] = 0;
        }
        *(uint4*)&kc[(((size_t)bh) * NPAD + pn) * 32 + q * 8] = o.u;
    }
    // ---- cb + kmp ----
    for (int i = t; i < npn; i += 256) {
        int pn = pn0 + i;
        int n = pn - 48; n = n < 0 ? 0 : (n > Nv - 1 ? Nv - 1 : n);
        size_t g = (size_t)b * Nv + n;
        cb[(size_t)bh * NPAD + pn] = -0.5f * hw * ksq[g * Hv + h];
        if (h == 0) kmp[(size_t)b * NPAD + pn] = (pn >= 48 && pn < 48 + Nv) ? smask[g] : 0.f;
    }
    // ---- qc rows (S1-scaled ch + hw-scaled pts + 4 zero) + rb, real rows ----
    for (int i = t; i < 512; i += 256) {
        int r = i >> 2, q = i & 3;
        int n = pn0 - 48 + r;
        if (n >= 0 && n < Nv) {
            size_t g = (size_t)b * Nv + n;
            BF8 o;
            if (q < 2) {
                const float* src = proj + g * PROJW + h * 16 + q * 8;
                #pragma unroll
                for (int j = 0; j < 8; ++j) o.s[j] = f2bf(S1 * src[j]);
            } else if (q == 2) {
                const float* src = qpts + g * QPD + h * 12;
                #pragma unroll
                for (int j = 0; j < 8; ++j) o.s[j] = f2bf(hw * src[j]);
            } else {
                const float* src = qpts + g * QPD + h * 12 + 8;
                #pragma unroll
                for (int j = 0; j < 4; ++j) o.s[j] = f2bf(hw * src[j]);
                o.s[4] = o.s[5] = o.s[6] = o.s[7] = 0;
            }
            *(uint4*)&qc[(((size_t)bh) * Nv + n) * 32 + q * 8] = o.u;
            if (q == 0) rb[(size_t)bh * Nv + n] = -0.5f * hw * qsq[g * Hv + h];
        }
    }
    // ---- vTc: transpose tile via LDS ----
    for (int i = t; i < npn * 10; i += 256) {
        int r = i / 10, q = i % 10;
        int pn = pn0 + r;
        int n = pn - 48; n = n < 0 ? 0 : (n > Nv - 1 ? Nv - 1 : n);
        size_t g = (size_t)b * Nv + n;
        float4 v = (q < 4) ? *(const float4*)&proj[g * PROJW + 384 + h * 16 + q * 4]
                           : *(const float4*)&vpts[g * (Hv * PVv * 3) + h * 24 + (q - 4) * 4];
        int c0 = q * 4;
        vt[(c0 + 0) * 136 + r] = f2bf(v.x);
        vt[(c0 + 1) * 136 + r] = f2bf(v.y);
        vt[(c0 + 2) * 136 + r] = f2bf(v.z);
        vt[(c0 + 3) * 136 + r] = f2bf(v.w);
    }
    __syncthreads();
    for (int i = t; i < 640; i += 256) {
        int c = i >> 4, s = i & 15;
        if (s * 8 < npn)
            *(uint4*)&vTc[((size_t)bh * 40 + c) * NPAD + pn0 + s * 8] = *(const uint4*)&vt[c * 136 + s * 8];
    }
}

// ---------------- K5a: attention logits+softmax+AV (pure-copy staging) ----------------
// grid = B*NBLK*6 head-pairs; 512 thr; LDS ~52.7 KB -> 3 blocks/CU.
__global__ __launch_bounds__(512, 6) void k_attn_main(const short* __restrict__ kc,
                                                      const short* __restrict__ qc,
                                                      const short* __restrict__ vTc,
                                                      const float* __restrict__ cb,
                                                      const float* __restrict__ rb,
                                                      const float* __restrict__ kmp,
                                                      const float* __restrict__ smask,
                                                      const short* __restrict__ bbias2,
                                                      short* __restrict__ Aws,
                                                      float* __restrict__ optraw,
                                                      float* __restrict__ feats) {
    __shared__ short kfrag[128 * 40];
    __shared__ short qfrag[32 * 40];
    __shared__ short vtileT[48 * 136];
    __shared__ float sc[32 * 132];
    __shared__ short Abuf[32 * 136];
    __shared__ float rowb[32], qmL[32], colb[128], kmL[128];

    int t = threadIdx.x;
    int hp = blockIdx.x % 6;
    int bblk = blockIdx.x / 6;
    int b = bblk >> 6, blk = bblk & 63;
    int wv = t >> 6, lane = t & 63;
    int lr = lane & 15, quad = lane >> 4;
    int n0 = blk * BQv;                       // padded window start (== blk*32-48+48)

    if (t < 128) kmL[t] = kmp[(size_t)b * NPAD + n0 + t];
    if (t < 32)  qmL[t] = smask[(size_t)b * Nv + n0 + t];
    {   // zero pad rows 40..47 of vtileT once
        int c = 40 + (t >> 6), k2 = (t & 63) * 2;
        *(unsigned*)&vtileT[c * 136 + k2] = 0;
    }
    __syncthreads();

    for (int hh = 0; hh < 2; ++hh) {
        int h = hp * 2 + hh;
        size_t bh = (size_t)b * 12 + h;

        // ---- stage: pure contiguous copies ----
        {
            int r = t >> 2, s8 = (t & 3) * 8;
            *(uint4*)&kfrag[r * 40 + s8] = *(const uint4*)&kc[(bh * NPAD + n0 + r) * 32 + s8];
        }
        if (t < 128) {
            int r = t >> 2, s8 = (t & 3) * 8;
            *(uint4*)&qfrag[r * 40 + s8] = *(const uint4*)&qc[(bh * Nv + n0 + r) * 32 + s8];
        }
        if (t < 128) colb[t] = cb[bh * NPAD + n0 + t];
        if (t < 32)  rowb[t] = rb[bh * Nv + n0 + t];
        for (int i = t; i < 640; i += 512) {
            int c = i >> 4, s8 = (i & 15) * 8;
            *(uint4*)&vtileT[c * 136 + s8] = *(const uint4*)&vTc[(bh * 40 + c) * NPAD + n0 + s8];
        }
        __syncthreads();

        // ---- logits MFMA ----
        f32x4 d[2];
        d[0] = 0; d[1] = 0;
        {
            bf16x8 bfr = *(const bf16x8*)&kfrag[(wv * 16 + lr) * 40 + quad * 8];
            bf16x8 a0 = *(const bf16x8*)&qfrag[lr * 40 + quad * 8];
            bf16x8 a1 = *(const bf16x8*)&qfrag[(16 + lr) * 40 + quad * 8];
            d[0] = __builtin_amdgcn_mfma_f32_16x16x32_bf16(a0, bfr, d[0], 0, 0, 0);
            d[1] = __builtin_amdgcn_mfma_f32_16x16x32_bf16(a1, bfr, d[1], 0, 0, 0);
        }
        {
            const short* bb = bbias2 + (size_t)(bblk * 12 + h) * 4096;
            #pragma unroll
            for (int mt = 0; mt < 2; ++mt) {
                #pragma unroll
                for (int r = 0; r < 4; ++r) {
                    int q = mt * 16 + quad * 4 + r;
                    int k = wv * 16 + lr;
                    float logit = d[mt][r] + rowb[q] + colb[k]
                                + 1e5f * (qmL[q] * kmL[k] - 1.f)
                                + bf2f(bb[q * 128 + k]);
                    sc[q * 132 + k] = logit;
                }
            }
        }
        __syncthreads();

        // ---- softmax ----
        {
            int q = t >> 4, i0 = (t & 15) * 8;
            float v[8];
            float m = -3.0e38f;
            #pragma unroll
            for (int j = 0; j < 8; ++j) { v[j] = sc[q * 132 + i0 + j]; m = fmaxf(m, v[j]); }
            #pragma unroll
            for (int off = 1; off <= 8; off <<= 1) m = fmaxf(m, __shfl_xor(m, off, 64));
            float ssum = 0.f;
            #pragma unroll
            for (int j = 0; j < 8; ++j) { v[j] = __expf(v[j] - m); ssum += v[j]; }
            #pragma unroll
            for (int off = 1; off <= 8; off <<= 1) ssum += __shfl_xor(ssum, off, 64);
            float inv = 1.f / ssum;
            short a8[8];
            #pragma unroll
            for (int j = 0; j < 8; ++j) a8[j] = f2bf(v[j] * inv);
            uint4 packed = make_uint4(pk2(a8[0], a8[1]), pk2(a8[2], a8[3]),
                                      pk2(a8[4], a8[5]), pk2(a8[6], a8[7]));
            *(uint4*)&Abuf[q * 136 + i0] = packed;
            *(uint4*)&Aws[((size_t)(bblk * 32 + q) * 12 + h) * 128 + i0] = packed;
        }
        __syncthreads();

        // ---- AV MFMA ----
        if (wv < 6) {
            int mt = wv & 1, nt = wv >> 1;
            f32x4 acc = 0;
            #pragma unroll
            for (int kt = 0; kt < 4; ++kt) {
                bf16x8 a = *(const bf16x8*)&Abuf[(mt * 16 + lr) * 136 + quad * 8 + kt * 32];
                bf16x8 bv = *(const bf16x8*)&vtileT[(nt * 16 + lr) * 136 + quad * 8 + kt * 32];
                acc = __builtin_amdgcn_mfma_f32_16x16x32_bf16(a, bv, acc, 0, 0, 0);
            }
            int c = nt * 16 + lr;
            #pragma unroll
            for (int r = 0; r < 4; ++r) {
                int q = mt * 16 + quad * 4 + r;
                size_t nqg = (size_t)b * Nv + n0 + q;
                if (c < 16) feats[nqg * FEAT + h * 16 + c] = acc[r];
                else if (c < 40) optraw[nqg * 288 + h * 24 + (c - 16)] = acc[r];
            }
        }
        __syncthreads();
    }
}

// ---------------- K5b: o_pair + rotation + feats (operands direct from global) ----------------
__global__ __launch_bounds__(64) void k_pair(const short* __restrict__ Aws,
                                             const short* __restrict__ pairzT,
                                             const float* __restrict__ optraw,
                                             const float* __restrict__ rots,
                                             const float* __restrict__ trans,
                                             float* __restrict__ feats) {
    __shared__ float Rt[12];
    int t = threadIdx.x;
    int bid = blockIdx.x;          // == nqg
    int lr = t & 15, quad = t >> 4;

    if (t < 9) Rt[t] = rots[(size_t)bid * 9 + t];
    if (t < 3) Rt[9 + t] = trans[(size_t)bid * 3 + t];
    __syncthreads();

    const short* Ab = Aws + (size_t)bid * 1536;
    const short* Pb = pairzT + (size_t)bid * 4096;
    f32x4 acc0 = 0, acc1 = 0;
    #pragma unroll
    for (int kt = 0; kt < 4; ++kt) {
        int ko = kt * 32 + quad * 8;
        bf16x8 a = 0;
        if (lr < 12) a = *(const bf16x8*)&Ab[lr * 128 + ko];
        bf16x8 b0 = *(const bf16x8*)&Pb[lr * 128 + ko];
        bf16x8 b1 = *(const bf16x8*)&Pb[(16 + lr) * 128 + ko];
        acc0 = __builtin_amdgcn_mfma_f32_16x16x32_bf16(a, b0, acc0, 0, 0, 0);
        acc1 = __builtin_amdgcn_mfma_f32_16x16x32_bf16(a, b1, acc1, 0, 0, 0);
    }
    float* frow = feats + (size_t)bid * FEAT;
    #pragma unroll
    for (int r = 0; r < 4; ++r) {
        int hh = quad * 4 + r;
        if (hh < 12) {
            frow[576 + hh * 32 + lr] = acc0[r];
            frow[576 + hh * 32 + 16 + lr] = acc1[r];
        }
    }

    for (int p = t; p < 96; p += 64) {
        float x = optraw[(size_t)bid * 288 + p * 3 + 0] - Rt[9];
        float y = optraw[(size_t)bid * 288 + p * 3 + 1] - Rt[10];
        float z = optraw[(size_t)bid * 288 + p * 3 + 2] - Rt[11];
        float lx = Rt[0] * x + Rt[3] * y + Rt[6] * z;
        float ly = Rt[1] * x + Rt[4] * y + Rt[7] * z;
        float lz = Rt[2] * x + Rt[5] * y + Rt[8] * z;
        frow[192 + p * 3 + 0] = lx;
        frow[192 + p * 3 + 1] = ly;
        frow[192 + p * 3 + 2] = lz;
        frow[480 + p] = sqrtf(lx * lx + ly * ly + lz * lz + 1e-8f);
    }
}

// ---------------- K6: out = feats @ Wout^T (fp32, b128 LDS reads) ----------------
__global__ __launch_bounds__(256) void k_out(const float* __restrict__ A,
                                             const float* __restrict__ Wo,
                                             float* __restrict__ C) {
    __shared__ float As[32][68];
    __shared__ float Bs[32][68];
    int t = threadIdx.x;
    int m0 = blockIdx.x * 64;
    int c0 = blockIdx.y * 64;
    int tx = t & 15, ty = t >> 4;
    int lr = t >> 2, lk = (t & 3) * 8;
    float acc[4][4] = {};
    for (int k0 = 0; k0 < FEAT; k0 += 32) {
        const float4* ap = (const float4*)(A + (size_t)(m0 + lr) * FEAT + k0 + lk);
        const float4* bp = (const float4*)(Wo + (size_t)(c0 + lr) * FEAT + k0 + lk);
        float4 a0 = ap[0], a1 = ap[1];
        float4 b0 = bp[0], b1 = bp[1];
        As[lk + 0][lr] = a0.x; As[lk + 1][lr] = a0.y; As[lk + 2][lr] = a0.z; As[lk + 3][lr] = a0.w;
        As[lk + 4][lr] = a1.x; As[lk + 5][lr] = a1.y; As[lk + 6][lr] = a1.z; As[lk + 7][lr] = a1.w;
        Bs[lk + 0][lr] = b0.x; Bs[lk + 1][lr] = b0.y; Bs[lk + 2][lr] = b0.z; Bs[lk + 3][lr] = b0.w;
        Bs[lk + 4][lr] = b1.x; Bs[lk + 5][lr] = b1.y; Bs[lk + 6][lr] = b1.z; Bs[lk + 7][lr] = b1.w;
        __syncthreads();
        #pragma unroll
        for (int kk = 0; kk < 32; ++kk) {
            float4 a4 = *(const float4*)&As[kk][ty * 4];
            float4 b4 = *(const float4*)&Bs[kk][tx * 4];
            float av[4] = {a4.x, a4.y, a4.z, a4.w};
            float bv[4] = {b4.x, b4.y, b4.z, b4.w};
            #pragma unroll
            for (int i = 0; i < 4; ++i)
                #pragma unroll
                for (int j = 0; j < 4; ++j) acc[i][j] += av[i] * bv[j];
        }
        __syncthreads();
    }
    #pragma unroll
    for (int i = 0; i < 4; ++i)
        #pragma unroll
        for (int j = 0; j < 4; ++j)
            C[(size_t)(m0 + ty * 4 + i) * CSv + c0 + tx * 4 + j] = acc[i][j];
}

// ---------------- launch ----------------
extern "C" void kernel_launch(void* const* d_in, const int* in_sizes, int n_in,
                              void* d_out, int out_size, void* d_ws, size_t ws_size,
                              hipStream_t stream) {
    const float* s          = (const float*)d_in[0];
    const float* cond       = (const float*)d_in[1];
    const float* z          = (const float*)d_in[2];
    const float* trans      = (const float*)d_in[3];
    const float* rots       = (const float*)d_in[4];
    const float* smask      = (const float*)d_in[5];
    const int*   cidx       = (const int*)d_in[6];
    const float* ln_cond_w  = (const float*)d_in[7];
    const float* lin_cond_W = (const float*)d_in[8];
    const float* lin_cond_b = (const float*)d_in[9];
    const float* lin_cond_nb_W = (const float*)d_in[10];
    const float* ln_z_w     = (const float*)d_in[11];
    const float* ln_z_b     = (const float*)d_in[12];
    const float* Wq         = (const float*)d_in[13];
    const float* Wk         = (const float*)d_in[14];
    const float* Wv         = (const float*)d_in[15];
    const float* Wqp        = (const float*)d_in[16];
    const float* Wkvp       = (const float*)d_in[17];
    const float* Wb         = (const float*)d_in[18];
    const float* Wdz        = (const float*)d_in[19];
    const float* head_w     = (const float*)d_in[20];
    const float* Wout       = (const float*)d_in[21];
    float* out = (float*)d_out;

    float* p = (float*)d_ws;
    short* wp = (short*)p; p += 3072;
    float* SBp = p; p += 96;
    short* wsW  = (short*)p; p += 221184;   // 1152*384 bf16
    short* wsW2 = (short*)p; p += 98304;    // 768*256 bf16
    short* cnbf = (short*)p; p += 65536;    // 512*256 bf16
    float* gb   = p; p += (size_t)512 * 768;
    short* s2bf = (short*)p; p += (size_t)Bv * Nv * CSv / 2;
    float* proj = p; p += (size_t)Bv * Nv * PROJW;
    float* qpts = p; p += (size_t)Bv * Nv * QPD;
    float* kpts = p; p += (size_t)Bv * Nv * QPD;
    float* vpts = p; p += (size_t)Bv * Nv * (Hv * PVv * 3);
    float* qsq  = p; p += (size_t)Bv * Nv * Hv;
    float* ksq  = p; p += (size_t)Bv * Nv * Hv;
    short* bbias2 = (short*)p; p += (size_t)128 * 12 * 4096 / 2;
    short* pairzT = (short*)p; p += (size_t)128 * 32 * 32 * 64;
    short* Aws    = (short*)p; p += (size_t)4096 * 12 * 64;
    float* optraw = p; p += (size_t)4096 * 288;
    float* feats  = p; p += (size_t)Bv * Nv * FEAT;
    short* kc  = (short*)p; p += (size_t)Bv * 12 * NPAD * 32 / 2;
    short* qc  = (short*)p; p += (size_t)Bv * 12 * Nv * 32 / 2;
    short* vTc = (short*)p; p += (size_t)Bv * 12 * 40 * NPAD / 2;
    float* cbw = p; p += (size_t)Bv * 12 * NPAD;
    float* rbw = p; p += (size_t)Bv * 12 * Nv;
    float* kmp = p; p += (size_t)Bv * NPAD;

    k_head<<<1137, 256, 0, stream>>>(Wq, Wk, Wv, Wqp, Wkvp, lin_cond_W, lin_cond_nb_W,
                                     wsW, wsW2, Wb, Wdz, ln_z_w, ln_z_b, wp, SBp,
                                     cond, ln_cond_w, cnbf);
    k_zg<<<4120, 256, 49280, stream>>>(z, wp, SBp, bbias2, pairzT, cnbf, wsW2, gb);
    k_s2<<<Bv * Nv, 128, 0, stream>>>(s, gb, lin_cond_b, cidx, smask, s2bf);
    k_gemm_bt<<<dim3(32, 9), 256, 0, stream>>>(s2bf, wsW, proj, CSv, PROJW);
    k_post<<<Bv * Nv, 192, 0, stream>>>(proj, rots, trans, qpts, kpts, vpts, qsq, ksq);
    k_kvcache<<<Bv * 12 * 17, 256, 0, stream>>>(proj, qpts, kpts, vpts, qsq, ksq,
                                                smask, head_w, kc, qc, vTc, cbw, rbw, kmp);
    k_attn_main<<<Bv * NBLKv * 6, 512, 0, stream>>>(kc, qc, vTc, cbw, rbw, kmp, smask,
                                                    bbias2, Aws, optraw, feats);
    k_pair<<<Bv * NBLKv * BQv, 64, 0, stream>>>(Aws, pairzT, optraw, rots, trans, feats);
    k_out<<<dim3(64, 6), 256, 0, stream>>>(feats, Wout, out);
}

// Round 3
// 548.227 us; speedup vs baseline: 1.1868x; 1.0586x over previous
//
#include <hip/hip_runtime.h>
#include <math.h>

// ---------------- constants ----------------
constexpr int Bv = 2, Nv = 2048, NCv = 256;
constexpr int CSv = 384, CCONDv = 256;
constexpr int CHv = 16, Hv = 12, PQKv = 4, PVv = 8;
constexpr int BQv = 32, BKv = 128, NBLKv = 64;
constexpr int HC = Hv * CHv;               // 192
constexpr int QPD = Hv * PQKv * 3;         // 144
constexpr int FEAT = 960;                  // H*CONCAT
constexpr int PROJW = 1152;                // q(192)+k(192)+v(192)+qp(144)+kvp(432)
constexpr int NPAD = 2144;                 // 48 + 2048 + 48 padded n-axis
constexpr float S1 = 0.14433756729740643f; // sqrt(1/48)
constexpr float S2 = 0.5773502691896258f;  // sqrt(1/3)
constexpr float HWS = 0.13608276348795434f;// sqrt(1/54)

typedef __attribute__((ext_vector_type(8))) short bf16x8;
typedef __attribute__((ext_vector_type(4))) float f32x4;

__device__ __forceinline__ short f2bf(float f) {
    unsigned u = __float_as_uint(f);
    u += 0x7FFF + ((u >> 16) & 1);
    return (short)(u >> 16);
}
__device__ __forceinline__ float bf2f(short s) {
    return __uint_as_float(((unsigned)(unsigned short)s) << 16);
}
__device__ __forceinline__ unsigned pk2(short lo, short hi) {
    return ((unsigned)(unsigned short)lo) | (((unsigned)(unsigned short)hi) << 16);
}
__device__ __forceinline__ void split2(float x, short& hi, short& lo) {
    hi = f2bf(x);
    lo = f2bf(x - bf2f(hi));
}

union BF8 { short s[8]; bf16x8 v; uint4 u; };

// ---------------- helpers ----------------
__device__ __forceinline__ float blockReduceSum(float v, volatile float* red, int t, int nthr) {
    #pragma unroll
    for (int off = 32; off > 0; off >>= 1) v += __shfl_down(v, off, 64);
    int wid = t >> 6, lane = t & 63, nw = nthr >> 6;
    __syncthreads();
    if (lane == 0) red[wid] = v;
    __syncthreads();
    float r = 0.f;
    for (int w = 0; w < nw; ++w) r += red[w];
    return r;
}

// ---------------- K0: merged head kernel: wcvt + prep + condln + Wout split ----------------
// 0..623: weight bf16 convert; 624: z-proj fold; 625..1136: LN(cond); 1137..1496: Wout hi/lo
__global__ __launch_bounds__(256) void k_head(const float* __restrict__ Wq,
                                              const float* __restrict__ Wk,
                                              const float* __restrict__ Wv,
                                              const float* __restrict__ Wqp,
                                              const float* __restrict__ Wkvp,
                                              const float* __restrict__ Wg,
                                              const float* __restrict__ Wnb,
                                              short* __restrict__ wsW,
                                              short* __restrict__ wsW2,
                                              const float* __restrict__ Wb,
                                              const float* __restrict__ Wdz,
                                              const float* __restrict__ lnzw,
                                              const float* __restrict__ lnzb,
                                              short* __restrict__ wp,
                                              float* __restrict__ SB,
                                              const float* __restrict__ cond,
                                              const float* __restrict__ lncw,
                                              short* __restrict__ cnbf,
                                              const float* __restrict__ Wout,
                                              short* __restrict__ WoutH,
                                              short* __restrict__ WoutL) {
    __shared__ float red[4];
    int bid = blockIdx.x;
    int t = threadIdx.x;
    if (bid < 624) {
        int off = (bid * 256 + t) * 4;
        const float* src;
        int rel;
        if (off < 442368) {
            rel = off;
            if (rel < 73728) src = Wq;
            else if (rel < 147456) { src = Wk; rel -= 73728; }
            else if (rel < 221184) { src = Wv; rel -= 147456; }
            else if (rel < 276480) { src = Wqp; rel -= 221184; }
            else { src = Wkvp; rel -= 276480; }
            float4 v = *(const float4*)(src + rel);
            *(uint2*)(wsW + off) = make_uint2(pk2(f2bf(v.x), f2bf(v.y)), pk2(f2bf(v.z), f2bf(v.w)));
        } else {
            int o2 = off - 442368;
            rel = o2;
            if (rel < 98304) src = Wg; else { src = Wnb; rel -= 98304; }
            float4 v = *(const float4*)(src + rel);
            *(uint2*)(wsW2 + o2) = make_uint2(pk2(f2bf(v.x), f2bf(v.y)), pk2(f2bf(v.z), f2bf(v.w)));
        }
    } else if (bid == 624) {
        if (t < 176) {
            int c = t >> 2, q = t & 3;
            const float* wrow = (c < 12) ? (Wb + (size_t)c * 128) : (Wdz + (size_t)(c - 12) * 128);
            float sacc = 0.f, bacc = 0.f;
            for (int i = q * 32; i < q * 32 + 32; ++i) {
                float wf = wrow[i] * lnzw[i];
                short bs = f2bf(wf);
                wp[c * 128 + i] = bs;
                sacc += bf2f(bs);
                bacc += lnzb[i] * wrow[i];
            }
            sacc += __shfl_xor(sacc, 1, 64); sacc += __shfl_xor(sacc, 2, 64);
            bacc += __shfl_xor(bacc, 1, 64); bacc += __shfl_xor(bacc, 2, 64);
            if (q == 0) { SB[c] = sacc; SB[48 + c] = bacc; }
        }
        for (int i = t; i < 512; i += 256) wp[44 * 128 + i] = 0;
        if (t >= 176 && t < 180) { SB[t - 132] = 0.f; SB[48 + t - 132] = 0.f; }
    } else if (bid < 1137) {
        int row = bid - 625;
        float c = cond[row * CCONDv + t];
        float mu = blockReduceSum(c, red, t, 256) * (1.f / CCONDv);
        float d = c - mu;
        float var = blockReduceSum(d * d, red, t, 256) * (1.f / CCONDv);
        cnbf[row * CCONDv + t] = f2bf(d * rsqrtf(var + 1e-5f) * lncw[t]);
    } else {
        int off = ((bid - 1137) * 256 + t) * 4;   // 360 blocks cover 368640 exactly
        float4 v = *(const float4*)(Wout + off);
        short h0, l0, h1, l1, h2, l2, h3, l3;
        split2(v.x, h0, l0); split2(v.y, h1, l1); split2(v.z, h2, l2); split2(v.w, h3, l3);
        *(uint2*)(WoutH + off) = make_uint2(pk2(h0, h1), pk2(h2, h3));
        *(uint2*)(WoutL + off) = make_uint2(pk2(l0, l1), pk2(l2, l3));
    }
}

// ---------------- proj GEMM: 128x64 tile, grid (32,18) -> 576 blocks ----------------
// C[m][n] = sum_k A[m][k]*B[n][k], K=384, ldc=1152
__global__ __launch_bounds__(256) void k_gemm_proj(const short* __restrict__ A,
                                                   const short* __restrict__ B,
                                                   float* __restrict__ C) {
    __shared__ short As[128 * 40];
    __shared__ short Bs[64 * 40];
    const int K = CSv, ldc = PROJW;
    int t = threadIdx.x;
    int m0 = blockIdx.x * 128, n0 = blockIdx.y * 64;
    int wv = t >> 6, lane = t & 63, lr = lane & 15, quad = lane >> 4;
    int mq = (wv & 1) * 64, nq = (wv >> 1) * 32;
    f32x4 acc[4][2];
    #pragma unroll
    for (int i = 0; i < 4; ++i)
        #pragma unroll
        for (int j = 0; j < 2; ++j) acc[i][j] = 0;

    int r0 = t >> 2, c8 = (t & 3) * 8;

    for (int k0 = 0; k0 < K; k0 += 32) {
        uint4 a0 = *(const uint4*)(A + (size_t)(m0 + r0) * K + k0 + c8);
        uint4 a1 = *(const uint4*)(A + (size_t)(m0 + r0 + 64) * K + k0 + c8);
        uint4 b0 = *(const uint4*)(B + (size_t)(n0 + r0) * K + k0 + c8);
        *(uint4*)&As[r0 * 40 + c8] = a0;
        *(uint4*)&As[(r0 + 64) * 40 + c8] = a1;
        *(uint4*)&Bs[r0 * 40 + c8] = b0;
        __syncthreads();
        bf16x8 af[4], bf[2];
        #pragma unroll
        for (int i = 0; i < 4; ++i) af[i] = *(const bf16x8*)&As[(mq + i * 16 + lr) * 40 + quad * 8];
        #pragma unroll
        for (int j = 0; j < 2; ++j) bf[j] = *(const bf16x8*)&Bs[(nq + j * 16 + lr) * 40 + quad * 8];
        #pragma unroll
        for (int i = 0; i < 4; ++i)
            #pragma unroll
            for (int j = 0; j < 2; ++j)
                acc[i][j] = __builtin_amdgcn_mfma_f32_16x16x32_bf16(af[i], bf[j], acc[i][j], 0, 0, 0);
        __syncthreads();
    }
    #pragma unroll
    for (int i = 0; i < 4; ++i) {
        #pragma unroll
        for (int j = 0; j < 2; ++j) {
            int col = n0 + nq + j * 16 + lr;
            #pragma unroll
            for (int r = 0; r < 4; ++r) {
                int row = m0 + mq + i * 16 + quad * 4 + r;
                C[(size_t)row * ldc + col] = acc[i][j][r];
            }
        }
    }
}

// ---------------- K2: LN(s) + gather gate/bias -> s2 (bf16) ----------------
__global__ __launch_bounds__(128) void k_s2(const float* __restrict__ s,
                                            const float* __restrict__ gb,
                                            const float* __restrict__ bg,
                                            const int* __restrict__ cidx,
                                            const float* __restrict__ smask,
                                            short* __restrict__ s2bf) {
    __shared__ float red[4];
    int row = blockIdx.x;
    int t = threadIdx.x;
    const float* sr = s + (size_t)row * CSv;
    float x0 = sr[t], x1 = sr[t + 128], x2 = sr[t + 256];
    float mu = blockReduceSum(x0 + x1 + x2, red, t, 128) * (1.f / CSv);
    float d0 = x0 - mu, d1 = x1 - mu, d2 = x2 - mu;
    float var = blockReduceSum(d0 * d0 + d1 * d1 + d2 * d2, red, t, 128) * (1.f / CSv);
    float rs = rsqrtf(var + 1e-5f);
    int b = row / Nv;
    int ci = cidx[row];
    float m = smask[row];
    const float* gbr = gb + (size_t)(b * NCv + ci) * 768;
    float dd[3] = {d0, d1, d2};
    #pragma unroll
    for (int j = 0; j < 3; ++j) {
        int cc = t + j * 128;
        float sn = dd[j] * rs;
        float g = (gbr[cc] + bg[cc]) * m, bi = gbr[384 + cc] * m;
        s2bf[(size_t)row * CSv + cc] = f2bf(sn * (1.f / (1.f + expf(-g))) + bi);
    }
}

// ---------------- K3b: point rotation + qsq/ksq from proj ----------------
__global__ __launch_bounds__(192) void k_post(const float* __restrict__ proj,
                                              const float* __restrict__ rots,
                                              const float* __restrict__ trans,
                                              float* __restrict__ qpts,
                                              float* __restrict__ kpts,
                                              float* __restrict__ vpts,
                                              float* __restrict__ qsq,
                                              float* __restrict__ ksq) {
    __shared__ float R[9], tr[3];
    int row = blockIdx.x;
    int t = threadIdx.x;
    if (t < 9) R[t] = rots[(size_t)row * 9 + t];
    if (t < 3) tr[t] = trans[(size_t)row * 3 + t];
    __syncthreads();
    const float* pr = proj + (size_t)row * PROJW + 576;
    float x = pr[t * 3 + 0], y = pr[t * 3 + 1], z = pr[t * 3 + 2];
    float ox = R[0] * x + R[1] * y + R[2] * z + tr[0];
    float oy = R[3] * x + R[4] * y + R[5] * z + tr[1];
    float oz = R[6] * x + R[7] * y + R[8] * z + tr[2];
    float sq = ox * ox + oy * oy + oz * oz;
    if (t < 48) {
        qpts[(size_t)row * QPD + t * 3 + 0] = ox;
        qpts[(size_t)row * QPD + t * 3 + 1] = oy;
        qpts[(size_t)row * QPD + t * 3 + 2] = oz;
        float s4 = sq + __shfl_xor(sq, 1, 64);
        s4 += __shfl_xor(s4, 2, 64);
        if ((t & 3) == 0) qsq[(size_t)row * Hv + (t >> 2)] = s4;
    } else {
        int p = t - 48;
        int h = p / 12, pp = p % 12;
        if (pp < PQKv) {
            kpts[(size_t)row * QPD + (h * PQKv + pp) * 3 + 0] = ox;
            kpts[(size_t)row * QPD + (h * PQKv + pp) * 3 + 1] = oy;
            kpts[(size_t)row * QPD + (h * PQKv + pp) * 3 + 2] = oz;
            float s4 = sq + __shfl_xor(sq, 1, 64);
            s4 += __shfl_xor(s4, 2, 64);
            if (pp == 0) ksq[(size_t)row * Hv + h] = s4;
        } else {
            int vi = h * PVv + pp - PQKv;
            vpts[(size_t)row * (Hv * PVv * 3) + vi * 3 + 0] = ox;
            vpts[(size_t)row * (Hv * PVv * 3) + vi * 3 + 1] = oy;
            vpts[(size_t)row * (Hv * PVv * 3) + vi * 3 + 2] = oz;
        }
    }
}

// ---------------- K4: merged zproj (blocks 0..4095) + cond GEMM (4096..4119) ----------------
__global__ __launch_bounds__(256) void k_zg(const float* __restrict__ z,
                                            const short* __restrict__ wp,
                                            const float* __restrict__ SB,
                                            short* __restrict__ bbias2,
                                            short* __restrict__ pairzT,
                                            const short* __restrict__ cnbf,
                                            const short* __restrict__ wsW2,
                                            float* __restrict__ gb) {
    extern __shared__ char smem[];
    int t = threadIdx.x;
    int bid = blockIdx.x;
    if (bid >= 4096) {
        short* As = (short*)smem;
        short* Bs = As + 128 * 40;
        int g = bid - 4096;
        int m0 = (g & 3) * 128, n0 = (g >> 2) * 128;
        const int K = CCONDv, ldc = 768;
        int wv = t >> 6, lane = t & 63, lr = lane & 15, quad = lane >> 4;
        int mq = (wv & 1) * 64, nq = (wv >> 1) * 64;
        f32x4 acc[4][4];
        #pragma unroll
        for (int i = 0; i < 4; ++i)
            #pragma unroll
            for (int j = 0; j < 4; ++j) acc[i][j] = 0;
        int r0 = t >> 2, c8 = (t & 3) * 8;
        int r1 = (t + 256) >> 2, c81 = ((t + 256) & 3) * 8;
        for (int k0 = 0; k0 < K; k0 += 32) {
            uint4 a0 = *(const uint4*)(cnbf + (size_t)(m0 + r0) * K + k0 + c8);
            uint4 a1 = *(const uint4*)(cnbf + (size_t)(m0 + r1) * K + k0 + c81);
            uint4 b0 = *(const uint4*)(wsW2 + (size_t)(n0 + r0) * K + k0 + c8);
            uint4 b1 = *(const uint4*)(wsW2 + (size_t)(n0 + r1) * K + k0 + c81);
            *(uint4*)&As[r0 * 40 + c8] = a0;
            *(uint4*)&As[r1 * 40 + c81] = a1;
            *(uint4*)&Bs[r0 * 40 + c8] = b0;
            *(uint4*)&Bs[r1 * 40 + c81] = b1;
            __syncthreads();
            bf16x8 af[4], bf[4];
            #pragma unroll
            for (int i = 0; i < 4; ++i) {
                af[i] = *(const bf16x8*)&As[(mq + i * 16 + lr) * 40 + quad * 8];
                bf[i] = *(const bf16x8*)&Bs[(nq + i * 16 + lr) * 40 + quad * 8];
            }
            #pragma unroll
            for (int i = 0; i < 4; ++i)
                #pragma unroll
                for (int j = 0; j < 4; ++j)
                    acc[i][j] = __builtin_amdgcn_mfma_f32_16x16x32_bf16(af[i], bf[j], acc[i][j], 0, 0, 0);
            __syncthreads();
        }
        #pragma unroll
        for (int i = 0; i < 4; ++i)
            #pragma unroll
            for (int j = 0; j < 4; ++j) {
                int col = n0 + nq + j * 16 + lr;
                #pragma unroll
                for (int r = 0; r < 4; ++r) {
                    int row = m0 + mq + i * 16 + quad * 4 + r;
                    gb[(size_t)row * ldc + col] = acc[i][j][r];
                }
            }
        return;
    }
    short* zbuf = (short*)smem;
    short* wbuf = zbuf + 128 * 136;
    float* muL  = (float*)(wbuf + 48 * 136);
    float* rsL  = muL + 128;
    float* SL   = rsL + 128;
    float* BL   = SL + 48;

    int bblk = bid >> 5, qq = bid & 31;
    size_t row0 = (size_t)bid * 128;

    for (int idx = t; idx < 768; idx += 256) {
        int c = idx >> 4, k8 = idx & 15;
        uint4 v = *(const uint4*)(wp + c * 128 + k8 * 8);
        *(uint4*)&wbuf[c * 136 + k8 * 8] = v;
    }
    if (t < 96) {
        float v = SB[t];
        if (t < 48) SL[t] = v; else BL[t - 48] = v;
    }

    const float4* zsrc = (const float4*)(z + row0 * 128);
    #pragma unroll
    for (int it = 0; it < 16; ++it) {
        int f = it * 256 + t;
        int r = f >> 5, c4 = f & 31;
        float4 v = zsrc[f];
        short s0 = f2bf(v.x), s1 = f2bf(v.y), s2v = f2bf(v.z), s3 = f2bf(v.w);
        *(uint2*)&zbuf[r * 136 + c4 * 4] = make_uint2(pk2(s0, s1), pk2(s2v, s3));
        float sm = v.x + v.y + v.z + v.w;
        float sq = v.x * v.x + v.y * v.y + v.z * v.z + v.w * v.w;
        #pragma unroll
        for (int off = 1; off <= 16; off <<= 1) {
            sm += __shfl_xor(sm, off, 64);
            sq += __shfl_xor(sq, off, 64);
        }
        if ((t & 31) == 0) {
            float mu = sm * (1.f / 128.f);
            float var = sq * (1.f / 128.f) - mu * mu;
            muL[r] = mu;
            rsL[r] = rsqrtf(var + 1e-5f);
        }
    }
    __syncthreads();

    int wv = t >> 6, lane = t & 63;
    int lr = lane & 15, quad = lane >> 4;
    int mb = wv * 32;
    f32x4 acc[2][3];
    #pragma unroll
    for (int i = 0; i < 2; ++i)
        #pragma unroll
        for (int j = 0; j < 3; ++j) acc[i][j] = 0;
    #pragma unroll
    for (int kt = 0; kt < 4; ++kt) {
        int ko = kt * 32 + quad * 8;
        bf16x8 a0 = *(const bf16x8*)&zbuf[(mb + lr) * 136 + ko];
        bf16x8 a1 = *(const bf16x8*)&zbuf[(mb + 16 + lr) * 136 + ko];
        bf16x8 b0 = *(const bf16x8*)&wbuf[lr * 136 + ko];
        bf16x8 b1 = *(const bf16x8*)&wbuf[(16 + lr) * 136 + ko];
        bf16x8 b2 = *(const bf16x8*)&wbuf[(32 + lr) * 136 + ko];
        acc[0][0] = __builtin_amdgcn_mfma_f32_16x16x32_bf16(a0, b0, acc[0][0], 0, 0, 0);
        acc[0][1] = __builtin_amdgcn_mfma_f32_16x16x32_bf16(a0, b1, acc[0][1], 0, 0, 0);
        acc[0][2] = __builtin_amdgcn_mfma_f32_16x16x32_bf16(a0, b2, acc[0][2], 0, 0, 0);
        acc[1][0] = __builtin_amdgcn_mfma_f32_16x16x32_bf16(a1, b0, acc[1][0], 0, 0, 0);
        acc[1][1] = __builtin_amdgcn_mfma_f32_16x16x32_bf16(a1, b1, acc[1][1], 0, 0, 0);
        acc[1][2] = __builtin_amdgcn_mfma_f32_16x16x32_bf16(a1, b2, acc[1][2], 0, 0, 0);
    }

    short* bb_base = bbias2 + (size_t)(bblk * 12) * 4096 + qq * 128;
    short* pz_base = pairzT + (size_t)bid * 32 * 128;
    #pragma unroll
    for (int mt = 0; mt < 2; ++mt) {
        #pragma unroll
        for (int nt = 0; nt < 3; ++nt) {
            int col = nt * 16 + lr;
            int kbase = mb + mt * 16 + quad * 4;
            float ov[4];
            #pragma unroll
            for (int r4 = 0; r4 < 4; ++r4) {
                int rl = kbase + r4;
                ov[r4] = rsL[rl] * (acc[mt][nt][r4] - muL[rl] * SL[col]) + BL[col];
            }
            if (col < 12) {
                *(uint2*)&bb_base[(size_t)col * 4096 + kbase] =
                    make_uint2(pk2(f2bf(S2 * ov[0]), f2bf(S2 * ov[1])),
                               pk2(f2bf(S2 * ov[2]), f2bf(S2 * ov[3])));
            } else if (col < 44) {
                int c = col - 12;
                *(uint2*)&pz_base[c * 128 + kbase] =
                    make_uint2(pk2(f2bf(ov[0]), f2bf(ov[1])), pk2(f2bf(ov[2]), f2bf(ov[3])));
            }
        }
    }
}

// ---------------- K4c: bf16 K/Q/V operand cache ----------------
__global__ __launch_bounds__(256) void k_kvcache(const float* __restrict__ proj,
                                                 const float* __restrict__ qpts,
                                                 const float* __restrict__ kpts,
                                                 const float* __restrict__ vpts,
                                                 const float* __restrict__ qsq,
                                                 const float* __restrict__ ksq,
                                                 const float* __restrict__ smask,
                                                 const float* __restrict__ head_w,
                                                 short* __restrict__ kc,
                                                 short* __restrict__ qc,
                                                 short* __restrict__ vTc,
                                                 float* __restrict__ cb,
                                                 float* __restrict__ rb,
                                                 float* __restrict__ kmp) {
    __shared__ short vt[40 * 136];
    int t = threadIdx.x;
    int tile = blockIdx.x % 17;
    int bh = blockIdx.x / 17;
    int b = bh / 12, h = bh % 12;
    float hw = log1pf(expf(head_w[h])) * HWS;
    int pn0 = tile * 128;
    int npn = (pn0 + 128 <= NPAD) ? 128 : (NPAD - pn0);

    for (int i = t; i < npn * 4; i += 256) {
        int r = i >> 2, q = i & 3;
        int pn = pn0 + r;
        int n = pn - 48; n = n < 0 ? 0 : (n > Nv - 1 ? Nv - 1 : n);
        size_t g = (size_t)b * Nv + n;
        BF8 o;
        if (q < 2) {
            const float* src = proj + g * PROJW + 192 + h * 16 + q * 8;
            #pragma unroll
            for (int j = 0; j < 8; ++j) o.s[j] = f2bf(src[j]);
        } else if (q == 2) {
            const float* src = kpts + g * QPD + h * 12;
            #pragma unroll
            for (int j = 0; j < 8; ++j) o.s[j] = f2bf(src[j]);
        } else {
            const float* src = kpts + g * QPD + h * 12 + 8;
            #pragma unroll
            for (int j = 0; j < 4; ++j) o.s[j] = f2bf(src[j]);
            o.s[4] = o.s[5] = o.s[6] = o.s[7] = 0;
        }
        *(uint4*)&kc[(((size_t)bh) * NPAD + pn) * 32 + q * 8] = o.u;
    }
    for (int i = t; i < npn; i += 256) {
        int pn = pn0 + i;
        int n = pn - 48; n = n < 0 ? 0 : (n > Nv - 1 ? Nv - 1 : n);
        size_t g = (size_t)b * Nv + n;
        cb[(size_t)bh * NPAD + pn] = -0.5f * hw * ksq[g * Hv + h];
        if (h == 0) kmp[(size_t)b * NPAD + pn] = (pn >= 48 && pn < 48 + Nv) ? smask[g] : 0.f;
    }
    for (int i = t; i < 512; i += 256) {
        int r = i >> 2, q = i & 3;
        int n = pn0 - 48 + r;
        if (n >= 0 && n < Nv) {
            size_t g = (size_t)b * Nv + n;
            BF8 o;
            if (q < 2) {
                const float* src = proj + g * PROJW + h * 16 + q * 8;
                #pragma unroll
                for (int j = 0; j < 8; ++j) o.s[j] = f2bf(S1 * src[j]);
            } else if (q == 2) {
                const float* src = qpts + g * QPD + h * 12;
                #pragma unroll
                for (int j = 0; j < 8; ++j) o.s[j] = f2bf(hw * src[j]);
            } else {
                const float* src = qpts + g * QPD + h * 12 + 8;
                #pragma unroll
                for (int j = 0; j < 4; ++j) o.s[j] = f2bf(hw * src[j]);
                o.s[4] = o.s[5] = o.s[6] = o.s[7] = 0;
            }
            *(uint4*)&qc[(((size_t)bh) * Nv + n) * 32 + q * 8] = o.u;
            if (q == 0) rb[(size_t)bh * Nv + n] = -0.5f * hw * qsq[g * Hv + h];
        }
    }
    for (int i = t; i < npn * 10; i += 256) {
        int r = i / 10, q = i % 10;
        int pn = pn0 + r;
        int n = pn - 48; n = n < 0 ? 0 : (n > Nv - 1 ? Nv - 1 : n);
        size_t g = (size_t)b * Nv + n;
        float4 v = (q < 4) ? *(const float4*)&proj[g * PROJW + 384 + h * 16 + q * 4]
                           : *(const float4*)&vpts[g * (Hv * PVv * 3) + h * 24 + (q - 4) * 4];
        int c0 = q * 4;
        vt[(c0 + 0) * 136 + r] = f2bf(v.x);
        vt[(c0 + 1) * 136 + r] = f2bf(v.y);
        vt[(c0 + 2) * 136 + r] = f2bf(v.z);
        vt[(c0 + 3) * 136 + r] = f2bf(v.w);
    }
    __syncthreads();
    for (int i = t; i < 640; i += 256) {
        int c = i >> 4, s = i & 15;
        if (s * 8 < npn)
            *(uint4*)&vTc[((size_t)bh * 40 + c) * NPAD + pn0 + s * 8] = *(const uint4*)&vt[c * 136 + s * 8];
    }
}

// ---------------- K5a: attention logits+softmax+AV (pure-copy staging) ----------------
__global__ __launch_bounds__(512, 6) void k_attn_main(const short* __restrict__ kc,
                                                      const short* __restrict__ qc,
                                                      const short* __restrict__ vTc,
                                                      const float* __restrict__ cb,
                                                      const float* __restrict__ rb,
                                                      const float* __restrict__ kmp,
                                                      const float* __restrict__ smask,
                                                      const short* __restrict__ bbias2,
                                                      short* __restrict__ Aws,
                                                      float* __restrict__ optraw,
                                                      float* __restrict__ feats) {
    __shared__ short kfrag[128 * 40];
    __shared__ short qfrag[32 * 40];
    __shared__ short vtileT[48 * 136];
    __shared__ float sc[32 * 132];
    __shared__ short Abuf[32 * 136];
    __shared__ float rowb[32], qmL[32], colb[128], kmL[128];

    int t = threadIdx.x;
    int hp = blockIdx.x % 6;
    int bblk = blockIdx.x / 6;
    int b = bblk >> 6, blk = bblk & 63;
    int wv = t >> 6, lane = t & 63;
    int lr = lane & 15, quad = lane >> 4;
    int n0 = blk * BQv;

    if (t < 128) kmL[t] = kmp[(size_t)b * NPAD + n0 + t];
    if (t < 32)  qmL[t] = smask[(size_t)b * Nv + n0 + t];
    {
        int c = 40 + (t >> 6), k2 = (t & 63) * 2;
        *(unsigned*)&vtileT[c * 136 + k2] = 0;
    }
    __syncthreads();

    for (int hh = 0; hh < 2; ++hh) {
        int h = hp * 2 + hh;
        size_t bh = (size_t)b * 12 + h;

        {
            int r = t >> 2, s8 = (t & 3) * 8;
            *(uint4*)&kfrag[r * 40 + s8] = *(const uint4*)&kc[(bh * NPAD + n0 + r) * 32 + s8];
        }
        if (t < 128) {
            int r = t >> 2, s8 = (t & 3) * 8;
            *(uint4*)&qfrag[r * 40 + s8] = *(const uint4*)&qc[(bh * Nv + n0 + r) * 32 + s8];
        }
        if (t < 128) colb[t] = cb[bh * NPAD + n0 + t];
        if (t < 32)  rowb[t] = rb[bh * Nv + n0 + t];
        for (int i = t; i < 640; i += 512) {
            int c = i >> 4, s8 = (i & 15) * 8;
            *(uint4*)&vtileT[c * 136 + s8] = *(const uint4*)&vTc[(bh * 40 + c) * NPAD + n0 + s8];
        }
        __syncthreads();

        f32x4 d[2];
        d[0] = 0; d[1] = 0;
        {
            bf16x8 bfr = *(const bf16x8*)&kfrag[(wv * 16 + lr) * 40 + quad * 8];
            bf16x8 a0 = *(const bf16x8*)&qfrag[lr * 40 + quad * 8];
            bf16x8 a1 = *(const bf16x8*)&qfrag[(16 + lr) * 40 + quad * 8];
            d[0] = __builtin_amdgcn_mfma_f32_16x16x32_bf16(a0, bfr, d[0], 0, 0, 0);
            d[1] = __builtin_amdgcn_mfma_f32_16x16x32_bf16(a1, bfr, d[1], 0, 0, 0);
        }
        {
            const short* bb = bbias2 + (size_t)(bblk * 12 + h) * 4096;
            #pragma unroll
            for (int mt = 0; mt < 2; ++mt) {
                #pragma unroll
                for (int r = 0; r < 4; ++r) {
                    int q = mt * 16 + quad * 4 + r;
                    int k = wv * 16 + lr;
                    float logit = d[mt][r] + rowb[q] + colb[k]
                                + 1e5f * (qmL[q] * kmL[k] - 1.f)
                                + bf2f(bb[q * 128 + k]);
                    sc[q * 132 + k] = logit;
                }
            }
        }
        __syncthreads();

        {
            int q = t >> 4, i0 = (t & 15) * 8;
            float v[8];
            float m = -3.0e38f;
            #pragma unroll
            for (int j = 0; j < 8; ++j) { v[j] = sc[q * 132 + i0 + j]; m = fmaxf(m, v[j]); }
            #pragma unroll
            for (int off = 1; off <= 8; off <<= 1) m = fmaxf(m, __shfl_xor(m, off, 64));
            float ssum = 0.f;
            #pragma unroll
            for (int j = 0; j < 8; ++j) { v[j] = __expf(v[j] - m); ssum += v[j]; }
            #pragma unroll
            for (int off = 1; off <= 8; off <<= 1) ssum += __shfl_xor(ssum, off, 64);
            float inv = 1.f / ssum;
            short a8[8];
            #pragma unroll
            for (int j = 0; j < 8; ++j) a8[j] = f2bf(v[j] * inv);
            uint4 packed = make_uint4(pk2(a8[0], a8[1]), pk2(a8[2], a8[3]),
                                      pk2(a8[4], a8[5]), pk2(a8[6], a8[7]));
            *(uint4*)&Abuf[q * 136 + i0] = packed;
            *(uint4*)&Aws[((size_t)(bblk * 32 + q) * 12 + h) * 128 + i0] = packed;
        }
        __syncthreads();

        if (wv < 6) {
            int mt = wv & 1, nt = wv >> 1;
            f32x4 acc = 0;
            #pragma unroll
            for (int kt = 0; kt < 4; ++kt) {
                bf16x8 a = *(const bf16x8*)&Abuf[(mt * 16 + lr) * 136 + quad * 8 + kt * 32];
                bf16x8 bv = *(const bf16x8*)&vtileT[(nt * 16 + lr) * 136 + quad * 8 + kt * 32];
                acc = __builtin_amdgcn_mfma_f32_16x16x32_bf16(a, bv, acc, 0, 0, 0);
            }
            int c = nt * 16 + lr;
            #pragma unroll
            for (int r = 0; r < 4; ++r) {
                int q = mt * 16 + quad * 4 + r;
                size_t nqg = (size_t)b * Nv + n0 + q;
                if (c < 16) feats[nqg * FEAT + h * 16 + c] = acc[r];
                else if (c < 40) optraw[nqg * 288 + h * 24 + (c - 16)] = acc[r];
            }
        }
        __syncthreads();
    }
}

// ---------------- K5b: o_pair + rotation + feats ----------------
__global__ __launch_bounds__(64) void k_pair(const short* __restrict__ Aws,
                                             const short* __restrict__ pairzT,
                                             const float* __restrict__ optraw,
                                             const float* __restrict__ rots,
                                             const float* __restrict__ trans,
                                             float* __restrict__ feats) {
    __shared__ float Rt[12];
    int t = threadIdx.x;
    int bid = blockIdx.x;
    int lr = t & 15, quad = t >> 4;

    if (t < 9) Rt[t] = rots[(size_t)bid * 9 + t];
    if (t < 3) Rt[9 + t] = trans[(size_t)bid * 3 + t];
    __syncthreads();

    const short* Ab = Aws + (size_t)bid * 1536;
    const short* Pb = pairzT + (size_t)bid * 4096;
    f32x4 acc0 = 0, acc1 = 0;
    #pragma unroll
    for (int kt = 0; kt < 4; ++kt) {
        int ko = kt * 32 + quad * 8;
        bf16x8 a = 0;
        if (lr < 12) a = *(const bf16x8*)&Ab[lr * 128 + ko];
        bf16x8 b0 = *(const bf16x8*)&Pb[lr * 128 + ko];
        bf16x8 b1 = *(const bf16x8*)&Pb[(16 + lr) * 128 + ko];
        acc0 = __builtin_amdgcn_mfma_f32_16x16x32_bf16(a, b0, acc0, 0, 0, 0);
        acc1 = __builtin_amdgcn_mfma_f32_16x16x32_bf16(a, b1, acc1, 0, 0, 0);
    }
    float* frow = feats + (size_t)bid * FEAT;
    #pragma unroll
    for (int r = 0; r < 4; ++r) {
        int hh = quad * 4 + r;
        if (hh < 12) {
            frow[576 + hh * 32 + lr] = acc0[r];
            frow[576 + hh * 32 + 16 + lr] = acc1[r];
        }
    }

    for (int p = t; p < 96; p += 64) {
        float x = optraw[(size_t)bid * 288 + p * 3 + 0] - Rt[9];
        float y = optraw[(size_t)bid * 288 + p * 3 + 1] - Rt[10];
        float z = optraw[(size_t)bid * 288 + p * 3 + 2] - Rt[11];
        float lx = Rt[0] * x + Rt[3] * y + Rt[6] * z;
        float ly = Rt[1] * x + Rt[4] * y + Rt[7] * z;
        float lz = Rt[2] * x + Rt[5] * y + Rt[8] * z;
        frow[192 + p * 3 + 0] = lx;
        frow[192 + p * 3 + 1] = ly;
        frow[192 + p * 3 + 2] = lz;
        frow[480 + p] = sqrtf(lx * lx + ly * ly + lz * lz + 1e-8f);
    }
}

// ---------------- K6: out = feats @ Wout^T via split-bf16 MFMA ----------------
// 32x128 tile, grid (128,3); A fp32 split to hi/lo on the fly; B pre-split.
__global__ __launch_bounds__(256) void k_out_mfma(const float* __restrict__ A,
                                                  const short* __restrict__ BhG,
                                                  const short* __restrict__ BlG,
                                                  float* __restrict__ C) {
    __shared__ short Ah[32 * 40];
    __shared__ short Al[32 * 40];
    __shared__ short Bh[128 * 40];
    __shared__ short Bl[128 * 40];
    int t = threadIdx.x;
    int m0 = blockIdx.x * 32, c0 = blockIdx.y * 128;
    int wv = t >> 6, lane = t & 63, lr = lane & 15, quad = lane >> 4;
    int nq = wv * 32;
    f32x4 acc[2][2];
    acc[0][0] = 0; acc[0][1] = 0; acc[1][0] = 0; acc[1][1] = 0;

    int ra = t >> 3, ca = (t & 7) * 4;
    int rb = t >> 2, s8 = (t & 3) * 8;

    for (int k0 = 0; k0 < FEAT; k0 += 32) {
        float4 av = *(const float4*)(A + (size_t)(m0 + ra) * FEAT + k0 + ca);
        short h0, l0, h1, l1, h2, l2, h3, l3;
        split2(av.x, h0, l0); split2(av.y, h1, l1); split2(av.z, h2, l2); split2(av.w, h3, l3);
        uint4 bh0 = *(const uint4*)(BhG + (size_t)(c0 + rb) * FEAT + k0 + s8);
        uint4 bh1 = *(const uint4*)(BhG + (size_t)(c0 + rb + 64) * FEAT + k0 + s8);
        uint4 bl0 = *(const uint4*)(BlG + (size_t)(c0 + rb) * FEAT + k0 + s8);
        uint4 bl1 = *(const uint4*)(BlG + (size_t)(c0 + rb + 64) * FEAT + k0 + s8);
        *(uint2*)&Ah[ra * 40 + ca] = make_uint2(pk2(h0, h1), pk2(h2, h3));
        *(uint2*)&Al[ra * 40 + ca] = make_uint2(pk2(l0, l1), pk2(l2, l3));
        *(uint4*)&Bh[rb * 40 + s8] = bh0;
        *(uint4*)&Bh[(rb + 64) * 40 + s8] = bh1;
        *(uint4*)&Bl[rb * 40 + s8] = bl0;
        *(uint4*)&Bl[(rb + 64) * 40 + s8] = bl1;
        __syncthreads();
        bf16x8 ah[2], al[2], bh[2], bl[2];
        #pragma unroll
        for (int mi = 0; mi < 2; ++mi) {
            ah[mi] = *(const bf16x8*)&Ah[(mi * 16 + lr) * 40 + quad * 8];
            al[mi] = *(const bf16x8*)&Al[(mi * 16 + lr) * 40 + quad * 8];
        }
        #pragma unroll
        for (int nj = 0; nj < 2; ++nj) {
            bh[nj] = *(const bf16x8*)&Bh[(nq + nj * 16 + lr) * 40 + quad * 8];
            bl[nj] = *(const bf16x8*)&Bl[(nq + nj * 16 + lr) * 40 + quad * 8];
        }
        #pragma unroll
        for (int mi = 0; mi < 2; ++mi)
            #pragma unroll
            for (int nj = 0; nj < 2; ++nj) {
                acc[mi][nj] = __builtin_amdgcn_mfma_f32_16x16x32_bf16(ah[mi], bh[nj], acc[mi][nj], 0, 0, 0);
                acc[mi][nj] = __builtin_amdgcn_mfma_f32_16x16x32_bf16(ah[mi], bl[nj], acc[mi][nj], 0, 0, 0);
                acc[mi][nj] = __builtin_amdgcn_mfma_f32_16x16x32_bf16(al[mi], bh[nj], acc[mi][nj], 0, 0, 0);
            }
        __syncthreads();
    }
    #pragma unroll
    for (int mi = 0; mi < 2; ++mi) {
        #pragma unroll
        for (int nj = 0; nj < 2; ++nj) {
            int col = c0 + nq + nj * 16 + lr;
            #pragma unroll
            for (int r = 0; r < 4; ++r) {
                int row = m0 + mi * 16 + quad * 4 + r;
                C[(size_t)row * CSv + col] = acc[mi][nj][r];
            }
        }
    }
}

// ---------------- launch ----------------
extern "C" void kernel_launch(void* const* d_in, const int* in_sizes, int n_in,
                              void* d_out, int out_size, void* d_ws, size_t ws_size,
                              hipStream_t stream) {
    const float* s          = (const float*)d_in[0];
    const float* cond       = (const float*)d_in[1];
    const float* z          = (const float*)d_in[2];
    const float* trans      = (const float*)d_in[3];
    const float* rots       = (const float*)d_in[4];
    const float* smask      = (const float*)d_in[5];
    const int*   cidx       = (const int*)d_in[6];
    const float* ln_cond_w  = (const float*)d_in[7];
    const float* lin_cond_W = (const float*)d_in[8];
    const float* lin_cond_b = (const float*)d_in[9];
    const float* lin_cond_nb_W = (const float*)d_in[10];
    const float* ln_z_w     = (const float*)d_in[11];
    const float* ln_z_b     = (const float*)d_in[12];
    const float* Wq         = (const float*)d_in[13];
    const float* Wk         = (const float*)d_in[14];
    const float* Wv         = (const float*)d_in[15];
    const float* Wqp        = (const float*)d_in[16];
    const float* Wkvp       = (const float*)d_in[17];
    const float* Wb         = (const float*)d_in[18];
    const float* Wdz        = (const float*)d_in[19];
    const float* head_w     = (const float*)d_in[20];
    const float* Wout       = (const float*)d_in[21];
    float* out = (float*)d_out;

    float* p = (float*)d_ws;
    short* wp = (short*)p; p += 3072;
    float* SBp = p; p += 96;
    short* wsW  = (short*)p; p += 221184;   // 1152*384 bf16
    short* wsW2 = (short*)p; p += 98304;    // 768*256 bf16
    short* cnbf = (short*)p; p += 65536;    // 512*256 bf16
    float* gb   = p; p += (size_t)512 * 768;
    short* s2bf = (short*)p; p += (size_t)Bv * Nv * CSv / 2;
    float* proj = p; p += (size_t)Bv * Nv * PROJW;
    float* qpts = p; p += (size_t)Bv * Nv * QPD;
    float* kpts = p; p += (size_t)Bv * Nv * QPD;
    float* vpts = p; p += (size_t)Bv * Nv * (Hv * PVv * 3);
    float* qsq  = p; p += (size_t)Bv * Nv * Hv;
    float* ksq  = p; p += (size_t)Bv * Nv * Hv;
    short* bbias2 = (short*)p; p += (size_t)128 * 12 * 4096 / 2;
    short* pairzT = (short*)p; p += (size_t)128 * 32 * 32 * 64;
    short* Aws    = (short*)p; p += (size_t)4096 * 12 * 64;
    float* optraw = p; p += (size_t)4096 * 288;
    float* feats  = p; p += (size_t)Bv * Nv * FEAT;
    short* kc  = (short*)p; p += (size_t)Bv * 12 * NPAD * 32 / 2;
    short* qc  = (short*)p; p += (size_t)Bv * 12 * Nv * 32 / 2;
    short* vTc = (short*)p; p += (size_t)Bv * 12 * 40 * NPAD / 2;
    float* cbw = p; p += (size_t)Bv * 12 * NPAD;
    float* rbw = p; p += (size_t)Bv * 12 * Nv;
    float* kmp = p; p += (size_t)Bv * NPAD;
    short* WoutH = (short*)p; p += (size_t)CSv * FEAT / 2;
    short* WoutL = (short*)p; p += (size_t)CSv * FEAT / 2;

    k_head<<<1497, 256, 0, stream>>>(Wq, Wk, Wv, Wqp, Wkvp, lin_cond_W, lin_cond_nb_W,
                                     wsW, wsW2, Wb, Wdz, ln_z_w, ln_z_b, wp, SBp,
                                     cond, ln_cond_w, cnbf, Wout, WoutH, WoutL);
    k_zg<<<4120, 256, 49280, stream>>>(z, wp, SBp, bbias2, pairzT, cnbf, wsW2, gb);
    k_s2<<<Bv * Nv, 128, 0, stream>>>(s, gb, lin_cond_b, cidx, smask, s2bf);
    k_gemm_proj<<<dim3(32, 18), 256, 0, stream>>>(s2bf, wsW, proj);
    k_post<<<Bv * Nv, 192, 0, stream>>>(proj, rots, trans, qpts, kpts, vpts, qsq, ksq);
    k_kvcache<<<Bv * 12 * 17, 256, 0, stream>>>(proj, qpts, kpts, vpts, qsq, ksq,
                                                smask, head_w, kc, qc, vTc, cbw, rbw, kmp);
    k_attn_main<<<Bv * NBLKv * 6, 512, 0, stream>>>(kc, qc, vTc, cbw, rbw, kmp, smask,
                                                    bbias2, Aws, optraw, feats);
    k_pair<<<Bv * NBLKv * BQv, 64, 0, stream>>>(Aws, pairzT, optraw, rots, trans, feats);
    k_out_mfma<<<dim3(128, 3), 256, 0, stream>>>(feats, WoutH, WoutL, out);
}